// Round 1
// 677.994 us; speedup vs baseline: 1.1804x; 1.1804x over previous
//
#include <hip/hip_runtime.h>
#include <cstdint>
#include <cstddef>

#define NN 50000
#define EE 800000
#define ETOT 850000   // EE + NN self loops
#define NEG_SLOPE 0.2f

typedef _Float16 f16;
typedef __attribute__((ext_vector_type(4))) _Float16 f16x4;

// ---------------- CSR build ----------------

__global__ __launch_bounds__(256) void deg_kernel(const int* __restrict__ ei, int* __restrict__ deg) {
    int e = blockIdx.x * 256 + threadIdx.x;
    if (e >= ETOT) return;
    int d = (e < EE) ? ei[EE + e] : (e - EE);
    atomicAdd(&deg[d], 1);
}

__global__ __launch_bounds__(256) void scan1_kernel(const int* __restrict__ deg, int* __restrict__ offs,
                                                    int* __restrict__ bsum, int n) {
    __shared__ int sh[256];
    int i = blockIdx.x * 256 + threadIdx.x;
    int v = (i < n) ? deg[i] : 0;
    sh[threadIdx.x] = v;
    __syncthreads();
    for (int off = 1; off < 256; off <<= 1) {
        int t = (threadIdx.x >= off) ? sh[threadIdx.x - off] : 0;
        __syncthreads();
        sh[threadIdx.x] += t;
        __syncthreads();
    }
    if (i < n) offs[i] = sh[threadIdx.x] - v;   // exclusive within block
    if (threadIdx.x == 255) bsum[blockIdx.x] = sh[255];
}

__global__ __launch_bounds__(256) void scan2_kernel(int* __restrict__ bsum, int nb) {
    __shared__ int sh[256];
    int v = (threadIdx.x < nb) ? bsum[threadIdx.x] : 0;
    sh[threadIdx.x] = v;
    __syncthreads();
    for (int off = 1; off < 256; off <<= 1) {
        int t = (threadIdx.x >= off) ? sh[threadIdx.x - off] : 0;
        __syncthreads();
        sh[threadIdx.x] += t;
        __syncthreads();
    }
    if (threadIdx.x < nb) bsum[threadIdx.x] = sh[threadIdx.x] - v;  // exclusive
}

__global__ __launch_bounds__(256) void scan3_kernel(const int* __restrict__ bsum, int* __restrict__ offs,
                                                    int* __restrict__ cursor, int n) {
    int i = blockIdx.x * 256 + threadIdx.x;
    if (i < n) {
        int o = offs[i] + bsum[blockIdx.x];
        offs[i] = o;
        cursor[i] = o;
    }
}

__global__ __launch_bounds__(256) void fill_kernel(const int* __restrict__ ei, int* __restrict__ cursor,
                                                   int* __restrict__ csrc, int* __restrict__ ceid) {
    int e = blockIdx.x * 256 + threadIdx.x;
    if (e >= ETOT) return;
    int d, s;
    if (e < EE) { s = ei[e]; d = ei[EE + e]; } else { s = e - EE; d = e - EE; }
    int p = atomicAdd(&cursor[d], 1);
    csrc[p] = s;
    ceid[p] = e;
}

// ---------------- GEMM (fp32 A[MxK] * B[KxN] -> fp16 C[MxN]) ----------------

__global__ __launch_bounds__(256) void gemm_kernel(const float* __restrict__ A, const float* __restrict__ B,
                                                   f16* __restrict__ C, int M, int N, int K) {
    __shared__ float As[64][20];
    __shared__ float Bs[16][64];
    int t = threadIdx.x;
    int tx = t & 15, ty = t >> 4;
    int m0 = blockIdx.y * 64;
    int n0 = blockIdx.x * 64;
    int arow = t >> 2;
    int acol = (t & 3) * 4;
    int brow = t >> 4;
    int bcol = (t & 15) * 4;
    float acc[4][4] = {};
    for (int k0 = 0; k0 < K; k0 += 16) {
        float4 av = make_float4(0.f, 0.f, 0.f, 0.f);
        int gr = m0 + arow;
        if (gr < M) av = *(const float4*)(A + (size_t)gr * K + k0 + acol);
        *(float4*)(&As[arow][acol]) = av;
        float4 bv = *(const float4*)(B + (size_t)(k0 + brow) * N + n0 + bcol);
        *(float4*)(&Bs[brow][bcol]) = bv;
        __syncthreads();
#pragma unroll
        for (int k = 0; k < 16; ++k) {
            float a0 = As[ty * 4 + 0][k];
            float a1 = As[ty * 4 + 1][k];
            float a2 = As[ty * 4 + 2][k];
            float a3 = As[ty * 4 + 3][k];
            float4 b4 = *(const float4*)(&Bs[k][tx * 4]);
            acc[0][0] += a0 * b4.x; acc[0][1] += a0 * b4.y; acc[0][2] += a0 * b4.z; acc[0][3] += a0 * b4.w;
            acc[1][0] += a1 * b4.x; acc[1][1] += a1 * b4.y; acc[1][2] += a1 * b4.z; acc[1][3] += a1 * b4.w;
            acc[2][0] += a2 * b4.x; acc[2][1] += a2 * b4.y; acc[2][2] += a2 * b4.z; acc[2][3] += a2 * b4.w;
            acc[3][0] += a3 * b4.x; acc[3][1] += a3 * b4.y; acc[3][2] += a3 * b4.z; acc[3][3] += a3 * b4.w;
        }
        __syncthreads();
    }
#pragma unroll
    for (int i = 0; i < 4; ++i) {
        int gr = m0 + ty * 4 + i;
        if (gr < M) {
            f16x4 v;
            v[0] = (f16)acc[i][0]; v[1] = (f16)acc[i][1]; v[2] = (f16)acc[i][2]; v[3] = (f16)acc[i][3];
            *(f16x4*)(C + (size_t)gr * N + n0 + tx * 4) = v;
        }
    }
}

// ---------------- attention score dots (fp16 H) ----------------

__global__ __launch_bounds__(256) void scores4_kernel(const f16* __restrict__ H, const float* __restrict__ aS,
                                                      const float* __restrict__ aD, float* __restrict__ es,
                                                      float* __restrict__ ed) {
    int wave = threadIdx.x >> 6, lane = threadIdx.x & 63;
    int n = blockIdx.x * 4 + wave;
    if (n >= NN) return;
    f16x4 h = *(const f16x4*)(H + (size_t)n * 256 + lane * 4);
    float4 s4 = *(const float4*)(aS + lane * 4);
    float4 d4 = *(const float4*)(aD + lane * 4);
    float hx = (float)h[0], hy = (float)h[1], hz = (float)h[2], hw = (float)h[3];
    float ps = hx * s4.x + hy * s4.y + hz * s4.z + hw * s4.w;
    float pd = hx * d4.x + hy * d4.y + hz * d4.z + hw * d4.w;
    for (int off = 1; off < 16; off <<= 1) { ps += __shfl_xor(ps, off); pd += __shfl_xor(pd, off); }
    if ((lane & 15) == 0) {
        int hh = lane >> 4;
        es[n * 4 + hh] = ps;
        ed[n * 4 + hh] = pd;
    }
}

__global__ __launch_bounds__(256) void scores_ms_kernel(const f16* __restrict__ H, const float* __restrict__ aS,
                                                        const float* __restrict__ aD, float* __restrict__ es,
                                                        float* __restrict__ ed) {
    int wave = threadIdx.x >> 6, lane = threadIdx.x & 63;
    int n = blockIdx.x * 4 + wave;
    if (n >= NN) return;
    float h = (float)H[(size_t)n * 64 + lane];
    float ps = h * aS[lane];
    float pd = h * aD[lane];
    for (int off = 1; off < 32; off <<= 1) { ps += __shfl_xor(ps, off); pd += __shfl_xor(pd, off); }
    if ((lane & 31) == 0) {
        int g = lane >> 5;
        es[n * 2 + g] = ps;
        ed[n * 2 + g] = pd;
    }
}

__device__ __forceinline__ float leaky(float v) { return v > 0.f ? v : NEG_SLOPE * v; }

// ---------------- softmax alpha (CSR order) for the 4-head layers ----------------

__device__ __forceinline__ void softmax4(
    int n, int lane, const float* __restrict__ es, const float* __restrict__ ed,
    const int* __restrict__ offs, const int* __restrict__ csrc, const int* __restrict__ ceid,
    float* __restrict__ etmp, float* __restrict__ alpha_out, int start, int deg) {
    int h = lane >> 4, sub = lane & 15;
    float edh = ed[n * 4 + h];
    float m = -INFINITY;
    for (int j = sub; j < deg; j += 16) {
        int s = csrc[start + j];
        float v = leaky(es[s * 4 + h] + edh);
        etmp[(size_t)(start + j) * 4 + h] = v;
        m = fmaxf(m, v);
    }
    for (int off = 1; off < 16; off <<= 1) m = fmaxf(m, __shfl_xor(m, off));
    float dsum = 0.f;
    for (int j = sub; j < deg; j += 16) {
        float t = __expf(etmp[(size_t)(start + j) * 4 + h] - m);
        etmp[(size_t)(start + j) * 4 + h] = t;
        dsum += t;
    }
    for (int off = 1; off < 16; off <<= 1) dsum += __shfl_xor(dsum, off);
    float inv = 1.f / (dsum + 1e-16f);
    for (int j = sub; j < deg; j += 16) {
        float a = etmp[(size_t)(start + j) * 4 + h] * inv;
        etmp[(size_t)(start + j) * 4 + h] = a;
        alpha_out[(size_t)ceid[start + j] * 4 + h] = a;
    }
}

// ---------------- layer-1 aggregation (concat heads, +bias, relu) ----------------
__global__ __launch_bounds__(256) void agg_concat_kernel(
    const f16* __restrict__ H, const float* __restrict__ es, const float* __restrict__ ed,
    const int* __restrict__ offs, const int* __restrict__ csrc, const int* __restrict__ ceid,
    const float* __restrict__ bias, float* __restrict__ out, float* __restrict__ alpha_out,
    float* __restrict__ etmp) {
    int wave = threadIdx.x >> 6, lane = threadIdx.x & 63;
    int n = blockIdx.x * 4 + wave;
    if (n >= NN) return;
    int h = lane >> 4;
    int start = offs[n];
    int end = (n + 1 < NN) ? offs[n + 1] : ETOT;
    int deg = end - start;
    softmax4(n, lane, es, ed, offs, csrc, ceid, etmp, alpha_out, start, deg);
    int cbase = lane * 4;
    float4 acc0 = {}, acc1 = {}, acc2 = {}, acc3 = {};
    int j = 0;
    for (; j + 3 < deg; j += 4) {
        int p = start + j;
        int s0 = csrc[p], s1 = csrc[p + 1], s2 = csrc[p + 2], s3 = csrc[p + 3];
        float a0 = etmp[(size_t)p * 4 + h];
        float a1 = etmp[(size_t)(p + 1) * 4 + h];
        float a2 = etmp[(size_t)(p + 2) * 4 + h];
        float a3 = etmp[(size_t)(p + 3) * 4 + h];
        f16x4 v0 = *(const f16x4*)(H + (size_t)s0 * 256 + cbase);
        f16x4 v1 = *(const f16x4*)(H + (size_t)s1 * 256 + cbase);
        f16x4 v2 = *(const f16x4*)(H + (size_t)s2 * 256 + cbase);
        f16x4 v3 = *(const f16x4*)(H + (size_t)s3 * 256 + cbase);
        acc0.x += a0 * (float)v0[0]; acc0.y += a0 * (float)v0[1]; acc0.z += a0 * (float)v0[2]; acc0.w += a0 * (float)v0[3];
        acc1.x += a1 * (float)v1[0]; acc1.y += a1 * (float)v1[1]; acc1.z += a1 * (float)v1[2]; acc1.w += a1 * (float)v1[3];
        acc2.x += a2 * (float)v2[0]; acc2.y += a2 * (float)v2[1]; acc2.z += a2 * (float)v2[2]; acc2.w += a2 * (float)v2[3];
        acc3.x += a3 * (float)v3[0]; acc3.y += a3 * (float)v3[1]; acc3.z += a3 * (float)v3[2]; acc3.w += a3 * (float)v3[3];
    }
    for (; j < deg; ++j) {
        int p = start + j;
        int s0 = csrc[p];
        float a0 = etmp[(size_t)p * 4 + h];
        f16x4 v0 = *(const f16x4*)(H + (size_t)s0 * 256 + cbase);
        acc0.x += a0 * (float)v0[0]; acc0.y += a0 * (float)v0[1]; acc0.z += a0 * (float)v0[2]; acc0.w += a0 * (float)v0[3];
    }
    float4 acc;
    acc.x = (acc0.x + acc1.x) + (acc2.x + acc3.x);
    acc.y = (acc0.y + acc1.y) + (acc2.y + acc3.y);
    acc.z = (acc0.z + acc1.z) + (acc2.z + acc3.z);
    acc.w = (acc0.w + acc1.w) + (acc2.w + acc3.w);
    float4 b = *(const float4*)(bias + cbase);
    acc.x = fmaxf(acc.x + b.x, 0.f);
    acc.y = fmaxf(acc.y + b.y, 0.f);
    acc.z = fmaxf(acc.z + b.z, 0.f);
    acc.w = fmaxf(acc.w + b.w, 0.f);
    *(float4*)(out + (size_t)n * 256 + cbase) = acc;
}

// ---------------- layer-2 aggregation (mean over 4 heads, +bias, relu) ----------------
__global__ __launch_bounds__(256) void agg_mean_kernel(
    const f16* __restrict__ H, const float* __restrict__ es, const float* __restrict__ ed,
    const int* __restrict__ offs, const int* __restrict__ csrc, const int* __restrict__ ceid,
    const float* __restrict__ bias, float* __restrict__ out, float* __restrict__ alpha_out,
    float* __restrict__ etmp) {
    int wave = threadIdx.x >> 6, lane = threadIdx.x & 63;
    int n = blockIdx.x * 4 + wave;
    if (n >= NN) return;
    int h = lane >> 4;
    int start = offs[n];
    int end = (n + 1 < NN) ? offs[n + 1] : ETOT;
    int deg = end - start;
    softmax4(n, lane, es, ed, offs, csrc, ceid, etmp, alpha_out, start, deg);
    int cbase = lane * 4;
    float4 acc0 = {}, acc1 = {}, acc2 = {}, acc3 = {};
    int j = 0;
    for (; j + 3 < deg; j += 4) {
        int p = start + j;
        int s0 = csrc[p], s1 = csrc[p + 1], s2 = csrc[p + 2], s3 = csrc[p + 3];
        float a0 = etmp[(size_t)p * 4 + h];
        float a1 = etmp[(size_t)(p + 1) * 4 + h];
        float a2 = etmp[(size_t)(p + 2) * 4 + h];
        float a3 = etmp[(size_t)(p + 3) * 4 + h];
        f16x4 v0 = *(const f16x4*)(H + (size_t)s0 * 256 + cbase);
        f16x4 v1 = *(const f16x4*)(H + (size_t)s1 * 256 + cbase);
        f16x4 v2 = *(const f16x4*)(H + (size_t)s2 * 256 + cbase);
        f16x4 v3 = *(const f16x4*)(H + (size_t)s3 * 256 + cbase);
        acc0.x += a0 * (float)v0[0]; acc0.y += a0 * (float)v0[1]; acc0.z += a0 * (float)v0[2]; acc0.w += a0 * (float)v0[3];
        acc1.x += a1 * (float)v1[0]; acc1.y += a1 * (float)v1[1]; acc1.z += a1 * (float)v1[2]; acc1.w += a1 * (float)v1[3];
        acc2.x += a2 * (float)v2[0]; acc2.y += a2 * (float)v2[1]; acc2.z += a2 * (float)v2[2]; acc2.w += a2 * (float)v2[3];
        acc3.x += a3 * (float)v3[0]; acc3.y += a3 * (float)v3[1]; acc3.z += a3 * (float)v3[2]; acc3.w += a3 * (float)v3[3];
    }
    for (; j < deg; ++j) {
        int p = start + j;
        int s0 = csrc[p];
        float a0 = etmp[(size_t)p * 4 + h];
        f16x4 v0 = *(const f16x4*)(H + (size_t)s0 * 256 + cbase);
        acc0.x += a0 * (float)v0[0]; acc0.y += a0 * (float)v0[1]; acc0.z += a0 * (float)v0[2]; acc0.w += a0 * (float)v0[3];
    }
    float4 acc;
    acc.x = (acc0.x + acc1.x) + (acc2.x + acc3.x);
    acc.y = (acc0.y + acc1.y) + (acc2.y + acc3.y);
    acc.z = (acc0.z + acc1.z) + (acc2.z + acc3.z);
    acc.w = (acc0.w + acc1.w) + (acc2.w + acc3.w);
    // sum across the 4 heads (lanes l, l^16, l^32, l^48 hold same channel)
    acc.x += __shfl_xor(acc.x, 16); acc.y += __shfl_xor(acc.y, 16);
    acc.z += __shfl_xor(acc.z, 16); acc.w += __shfl_xor(acc.w, 16);
    acc.x += __shfl_xor(acc.x, 32); acc.y += __shfl_xor(acc.y, 32);
    acc.z += __shfl_xor(acc.z, 32); acc.w += __shfl_xor(acc.w, 32);
    if (lane < 16) {
        float4 b = *(const float4*)(bias + lane * 4);
        float4 r;
        r.x = fmaxf(acc.x * 0.25f + b.x, 0.f);
        r.y = fmaxf(acc.y * 0.25f + b.y, 0.f);
        r.z = fmaxf(acc.z * 0.25f + b.z, 0.f);
        r.w = fmaxf(acc.w * 0.25f + b.w, 0.f);
        *(float4*)(out + (size_t)n * 64 + lane * 4) = r;
    }
}

// ---------------- mean/log_std heads aggregation (2 pseudo-heads of 32 ch) ----------------
__global__ __launch_bounds__(256) void agg_ms_kernel(
    const f16* __restrict__ H, const float* __restrict__ es, const float* __restrict__ ed,
    const int* __restrict__ offs, const int* __restrict__ csrc, const int* __restrict__ ceid,
    const float* __restrict__ bm, const float* __restrict__ bs,
    float* __restrict__ zmean, float* __restrict__ zlog,
    float* __restrict__ a_wm, float* __restrict__ a_ws,
    float* __restrict__ etmp) {
    int wave = threadIdx.x >> 6, lane = threadIdx.x & 63;
    int n = blockIdx.x * 4 + wave;
    if (n >= NN) return;
    int g = lane >> 5, sub = lane & 31;
    int start = offs[n];
    int end = (n + 1 < NN) ? offs[n + 1] : ETOT;
    int deg = end - start;
    float edh = ed[n * 2 + g];
    float m = -INFINITY;
    for (int j = sub; j < deg; j += 32) {
        int s = csrc[start + j];
        float v = leaky(es[s * 2 + g] + edh);
        etmp[(size_t)(start + j) * 2 + g] = v;
        m = fmaxf(m, v);
    }
    for (int off = 1; off < 32; off <<= 1) m = fmaxf(m, __shfl_xor(m, off));
    float dsum = 0.f;
    for (int j = sub; j < deg; j += 32) {
        float t = __expf(etmp[(size_t)(start + j) * 2 + g] - m);
        etmp[(size_t)(start + j) * 2 + g] = t;
        dsum += t;
    }
    for (int off = 1; off < 32; off <<= 1) dsum += __shfl_xor(dsum, off);
    float inv = 1.f / (dsum + 1e-16f);
    for (int j = sub; j < deg; j += 32) {
        float a = etmp[(size_t)(start + j) * 2 + g] * inv;
        etmp[(size_t)(start + j) * 2 + g] = a;
        int eid = ceid[start + j];
        if (g == 0) a_wm[eid] = a; else a_ws[eid] = a;
    }
    float acc0 = 0.f, acc1 = 0.f, acc2 = 0.f, acc3 = 0.f;
    int j = 0;
    for (; j + 3 < deg; j += 4) {
        int p = start + j;
        int s0 = csrc[p], s1 = csrc[p + 1], s2 = csrc[p + 2], s3 = csrc[p + 3];
        float a0 = etmp[(size_t)p * 2 + g];
        float a1 = etmp[(size_t)(p + 1) * 2 + g];
        float a2 = etmp[(size_t)(p + 2) * 2 + g];
        float a3 = etmp[(size_t)(p + 3) * 2 + g];
        acc0 += a0 * (float)H[(size_t)s0 * 64 + lane];
        acc1 += a1 * (float)H[(size_t)s1 * 64 + lane];
        acc2 += a2 * (float)H[(size_t)s2 * 64 + lane];
        acc3 += a3 * (float)H[(size_t)s3 * 64 + lane];
    }
    for (; j < deg; ++j) {
        int p = start + j;
        int s0 = csrc[p];
        float a0 = etmp[(size_t)p * 2 + g];
        acc0 += a0 * (float)H[(size_t)s0 * 64 + lane];
    }
    float acc = (acc0 + acc1) + (acc2 + acc3);
    if (g == 0) zmean[(size_t)n * 32 + sub] = acc + bm[sub];
    else        zlog[(size_t)n * 32 + sub] = acc + bs[sub];
}

// ---------------- pack combined mean/log_std weights ----------------
__global__ __launch_bounds__(256) void pack_ms_kernel(const float* __restrict__ Wm, const float* __restrict__ Ws,
                                                      const float* __restrict__ ams, const float* __restrict__ ass,
                                                      const float* __restrict__ amd, const float* __restrict__ asd,
                                                      float* __restrict__ Wms, float* __restrict__ aS,
                                                      float* __restrict__ aD) {
    int i = blockIdx.x * 256 + threadIdx.x;
    if (i < 4096) {
        int k = i >> 6, c = i & 63;
        Wms[i] = (c < 32) ? Wm[k * 32 + c] : Ws[k * 32 + (c - 32)];
    }
    if (i < 64) {
        aS[i] = (i < 32) ? ams[i] : ass[i - 32];
        aD[i] = (i < 32) ? amd[i] : asd[i - 32];
    }
}

// ---------------- launch ----------------

extern "C" void kernel_launch(void* const* d_in, const int* in_sizes, int n_in,
                              void* d_out, int out_size, void* d_ws, size_t ws_size,
                              hipStream_t stream) {
    const float* x   = (const float*)d_in[0];
    const int*   ei  = (const int*)d_in[1];
    const float* W1  = (const float*)d_in[2];
    const float* a1s = (const float*)d_in[3];
    const float* a1d = (const float*)d_in[4];
    const float* b1  = (const float*)d_in[5];
    const float* W2  = (const float*)d_in[6];
    const float* a2s = (const float*)d_in[7];
    const float* a2d = (const float*)d_in[8];
    const float* b2  = (const float*)d_in[9];
    const float* Wm  = (const float*)d_in[10];
    const float* ams = (const float*)d_in[11];
    const float* amd = (const float*)d_in[12];
    const float* bm  = (const float*)d_in[13];
    const float* Ws  = (const float*)d_in[14];
    const float* ass = (const float*)d_in[15];
    const float* asd = (const float*)d_in[16];
    const float* bs  = (const float*)d_in[17];

    float* out = (float*)d_out;
    float* zmean = out;                       // [50000,32]
    float* zlog  = out + 1600000;             // [50000,32]
    float* a_w1  = out + 3200000;             // [850000,4]
    float* a_w2  = out + 6600000;             // [850000,4]
    float* a_wm  = out + 10000000;            // [850000]
    float* a_ws_o = out + 10850000;           // [850000]

    float* ws = (float*)d_ws;
    size_t o = 0;
    f16*   Hh   = (f16*)(ws + o); o += (size_t)NN * 128;  // NN*256 halves, reused each layer
    float* bufB = ws + o; o += (size_t)NN * 256;   // h1relu (gemm2 A)
    float* h2   = ws + o; o += (size_t)NN * 64;
    float* etmp = ws + o; o += (size_t)ETOT * 4;   // CSR-order scores/alpha scratch
    float* es1  = ws + o; o += NN * 4;
    float* ed1  = ws + o; o += NN * 4;
    float* es2  = ws + o; o += NN * 4;
    float* ed2  = ws + o; o += NN * 4;
    float* esms = ws + o; o += NN * 2;
    float* edms = ws + o; o += NN * 2;
    float* Wms  = ws + o; o += 4096;
    float* aSms = ws + o; o += 64;
    float* aDms = ws + o; o += 64;
    int* deg    = (int*)(ws + o); o += NN;
    int* offs   = (int*)(ws + o); o += NN;
    int* cursor = (int*)(ws + o); o += NN;
    int* csrc   = (int*)(ws + o); o += ETOT;
    int* ceid   = (int*)(ws + o); o += ETOT;

    const int edgeBlocks = (ETOT + 255) / 256;   // 3321
    const int nodeBlocks = (NN + 255) / 256;     // 196
    const int waveBlocks = (NN + 3) / 4;         // 12500

    // ---- CSR build ----
    hipMemsetAsync(deg, 0, NN * sizeof(int), stream);
    deg_kernel<<<edgeBlocks, 256, 0, stream>>>(ei, deg);
    scan1_kernel<<<nodeBlocks, 256, 0, stream>>>(deg, offs, cursor /*tmp bsum*/, NN);
    scan2_kernel<<<1, 256, 0, stream>>>(cursor, nodeBlocks);
    scan3_kernel<<<nodeBlocks, 256, 0, stream>>>(cursor, offs, deg /*reuse as cursor*/, NN);
    fill_kernel<<<edgeBlocks, 256, 0, stream>>>(ei, deg, csrc, ceid);

    // ---- pack mean/log_std weights ----
    pack_ms_kernel<<<16, 256, 0, stream>>>(Wm, Ws, ams, ass, amd, asd, Wms, aSms, aDms);

    dim3 g1(4, (NN + 63) / 64);
    // ---- layer 1 ----
    gemm_kernel<<<g1, 256, 0, stream>>>(x, W1, Hh, NN, 256, 256);
    scores4_kernel<<<waveBlocks, 256, 0, stream>>>(Hh, a1s, a1d, es1, ed1);
    agg_concat_kernel<<<waveBlocks, 256, 0, stream>>>(Hh, es1, ed1, offs, csrc, ceid, b1, bufB, a_w1, etmp);

    // ---- layer 2 ----
    gemm_kernel<<<g1, 256, 0, stream>>>(bufB, W2, Hh, NN, 256, 256);
    scores4_kernel<<<waveBlocks, 256, 0, stream>>>(Hh, a2s, a2d, es2, ed2);
    agg_mean_kernel<<<waveBlocks, 256, 0, stream>>>(Hh, es2, ed2, offs, csrc, ceid, b2, h2, a_w2, etmp);

    // ---- mean / log_std heads ----
    dim3 g2(1, (NN + 63) / 64);
    gemm_kernel<<<g2, 256, 0, stream>>>(h2, Wms, Hh, NN, 64, 64);
    scores_ms_kernel<<<waveBlocks, 256, 0, stream>>>(Hh, aSms, aDms, esms, edms);
    agg_ms_kernel<<<waveBlocks, 256, 0, stream>>>(Hh, esms, edms, offs, csrc, ceid, bm, bs,
                                                  zmean, zlog, a_wm, a_ws_o, etmp);
}

// Round 2
// 569.618 us; speedup vs baseline: 1.4050x; 1.1903x over previous
//
#include <hip/hip_runtime.h>
#include <cstdint>
#include <cstddef>

#define NN 50000
#define EE 800000
#define ETOT 850000   // EE + NN self loops
#define NEG_SLOPE 0.2f

typedef _Float16 f16;
typedef __attribute__((ext_vector_type(4))) _Float16 f16x4;
typedef __attribute__((ext_vector_type(8))) _Float16 f16x8;
typedef __attribute__((ext_vector_type(4))) float f32x4;

// ---------------- CSR build ----------------

__global__ __launch_bounds__(256) void deg_kernel(const int* __restrict__ ei, int* __restrict__ deg) {
    int e = blockIdx.x * 256 + threadIdx.x;
    if (e >= ETOT) return;
    int d = (e < EE) ? ei[EE + e] : (e - EE);
    atomicAdd(&deg[d], 1);
}

__global__ __launch_bounds__(256) void scan1_kernel(const int* __restrict__ deg, int* __restrict__ offs,
                                                    int* __restrict__ bsum, int n) {
    __shared__ int sh[256];
    int i = blockIdx.x * 256 + threadIdx.x;
    int v = (i < n) ? deg[i] : 0;
    sh[threadIdx.x] = v;
    __syncthreads();
    for (int off = 1; off < 256; off <<= 1) {
        int t = (threadIdx.x >= off) ? sh[threadIdx.x - off] : 0;
        __syncthreads();
        sh[threadIdx.x] += t;
        __syncthreads();
    }
    if (i < n) offs[i] = sh[threadIdx.x] - v;   // exclusive within block
    if (threadIdx.x == 255) bsum[blockIdx.x] = sh[255];
}

__global__ __launch_bounds__(256) void scan2_kernel(int* __restrict__ bsum, int nb) {
    __shared__ int sh[256];
    int v = (threadIdx.x < nb) ? bsum[threadIdx.x] : 0;
    sh[threadIdx.x] = v;
    __syncthreads();
    for (int off = 1; off < 256; off <<= 1) {
        int t = (threadIdx.x >= off) ? sh[threadIdx.x - off] : 0;
        __syncthreads();
        sh[threadIdx.x] += t;
        __syncthreads();
    }
    if (threadIdx.x < nb) bsum[threadIdx.x] = sh[threadIdx.x] - v;  // exclusive
}

__global__ __launch_bounds__(256) void scan3_kernel(const int* __restrict__ bsum, int* __restrict__ offs,
                                                    int* __restrict__ cursor, int n) {
    int i = blockIdx.x * 256 + threadIdx.x;
    if (i < n) {
        int o = offs[i] + bsum[blockIdx.x];
        offs[i] = o;
        cursor[i] = o;
    }
}

__global__ __launch_bounds__(256) void fill_kernel(const int* __restrict__ ei, int* __restrict__ cursor,
                                                   int* __restrict__ csrc, int* __restrict__ ceid) {
    int e = blockIdx.x * 256 + threadIdx.x;
    if (e >= ETOT) return;
    int d, s;
    if (e < EE) { s = ei[e]; d = ei[EE + e]; } else { s = e - EE; d = e - EE; }
    int p = atomicAdd(&cursor[d], 1);
    csrc[p] = s;
    ceid[p] = e;
}

// ---------------- MFMA GEMM: A[MxK] (f32 or f16) * Wt[N][K]^T -> C f16 [MxN] ----------------
// BM=128 (4 waves x 32 rows), BN=64, no LDS. Fragment layouts (m89/m92-verified):
//   A-frag: lane l holds A[row=l&15][k0 + (l>>4)*8 + j], j=0..7 (contiguous 16B)
//   B-frag: lane l holds B[k0 + (l>>4)*8 + j][col=l&15]  == Wt[col][k...] (contiguous 16B)
//   C/D:    reg i -> row=(l>>4)*4+i, col=l&15

template<int K, bool AF32>
__global__ __launch_bounds__(256) void mfma_gemm(const void* __restrict__ Ap, const f16* __restrict__ Bt,
                                                 f16* __restrict__ C, int M, int N) {
    int w = threadIdx.x >> 6, lane = threadIdx.x & 63;
    int m0 = blockIdx.y * 128 + w * 32;
    int n0 = blockIdx.x * 64;
    int r = lane & 15, kb = lane >> 4;
    int ar0 = m0 + r;       if (ar0 > M - 1) ar0 = M - 1;
    int ar1 = m0 + 16 + r;  if (ar1 > M - 1) ar1 = M - 1;
    f32x4 acc[2][4] = {};
    const float* Af = (const float*)Ap;
    const f16*   Ah = (const f16*)Ap;
    size_t a0off = (size_t)ar0 * K + kb * 8;
    size_t a1off = (size_t)ar1 * K + kb * 8;
    const f16* bbase = Bt + (size_t)(n0 + r) * K + kb * 8;
    for (int k0 = 0; k0 < K; k0 += 32) {
        f16x8 a0, a1;
        if constexpr (AF32) {
            float4 l0 = *(const float4*)(Af + a0off + k0);
            float4 h0 = *(const float4*)(Af + a0off + k0 + 4);
            float4 l1 = *(const float4*)(Af + a1off + k0);
            float4 h1 = *(const float4*)(Af + a1off + k0 + 4);
            a0[0]=(f16)l0.x; a0[1]=(f16)l0.y; a0[2]=(f16)l0.z; a0[3]=(f16)l0.w;
            a0[4]=(f16)h0.x; a0[5]=(f16)h0.y; a0[6]=(f16)h0.z; a0[7]=(f16)h0.w;
            a1[0]=(f16)l1.x; a1[1]=(f16)l1.y; a1[2]=(f16)l1.z; a1[3]=(f16)l1.w;
            a1[4]=(f16)h1.x; a1[5]=(f16)h1.y; a1[6]=(f16)h1.z; a1[7]=(f16)h1.w;
        } else {
            a0 = *(const f16x8*)(Ah + a0off + k0);
            a1 = *(const f16x8*)(Ah + a1off + k0);
        }
#pragma unroll
        for (int ni = 0; ni < 4; ++ni) {
            f16x8 b = *(const f16x8*)(bbase + (size_t)ni * 16 * K + k0);
            acc[0][ni] = __builtin_amdgcn_mfma_f32_16x16x32_f16(a0, b, acc[0][ni], 0, 0, 0);
            acc[1][ni] = __builtin_amdgcn_mfma_f32_16x16x32_f16(a1, b, acc[1][ni], 0, 0, 0);
        }
    }
#pragma unroll
    for (int mi = 0; mi < 2; ++mi) {
#pragma unroll
        for (int i = 0; i < 4; ++i) {
            int row = m0 + mi * 16 + kb * 4 + i;
            if (row < M) {
#pragma unroll
                for (int ni = 0; ni < 4; ++ni)
                    C[(size_t)row * N + n0 + ni * 16 + r] = (f16)acc[mi][ni][i];
            }
        }
    }
}

// ---------------- pack weights: f16 + transpose (Wt[N][K]) ----------------

__global__ __launch_bounds__(256) void packw_kernel(const float* __restrict__ W1, const float* __restrict__ W2,
                                                    const float* __restrict__ Wm, const float* __restrict__ Ws,
                                                    const float* __restrict__ ams, const float* __restrict__ ass,
                                                    const float* __restrict__ amd, const float* __restrict__ asd,
                                                    f16* __restrict__ Wt1, f16* __restrict__ Wt2,
                                                    f16* __restrict__ Wtms,
                                                    float* __restrict__ aS, float* __restrict__ aD) {
    int i = blockIdx.x * 256 + threadIdx.x;
    if (i < 65536) {
        int n = i >> 8, k = i & 255;   // Wt[n][k] = W[k][n]
        Wt1[(size_t)n * 256 + k] = (f16)W1[(size_t)k * 256 + n];
        Wt2[(size_t)n * 256 + k] = (f16)W2[(size_t)k * 256 + n];
    }
    if (i < 4096) {
        int c = i >> 6, k = i & 63;    // Wtms[c][k]: c<32 -> Wm[k][c], else Ws[k][c-32]
        float v = (c < 32) ? Wm[k * 32 + c] : Ws[k * 32 + (c - 32)];
        Wtms[(size_t)c * 64 + k] = (f16)v;
    }
    if (i < 64) {
        aS[i] = (i < 32) ? ams[i] : ass[i - 32];
        aD[i] = (i < 32) ? amd[i] : asd[i - 32];
    }
}

// ---------------- attention score dots (fp16 H) ----------------

__global__ __launch_bounds__(256) void scores4_kernel(const f16* __restrict__ H, const float* __restrict__ aS,
                                                      const float* __restrict__ aD, float* __restrict__ es,
                                                      float* __restrict__ ed) {
    int wave = threadIdx.x >> 6, lane = threadIdx.x & 63;
    int n = blockIdx.x * 4 + wave;
    if (n >= NN) return;
    f16x4 h = *(const f16x4*)(H + (size_t)n * 256 + lane * 4);
    float4 s4 = *(const float4*)(aS + lane * 4);
    float4 d4 = *(const float4*)(aD + lane * 4);
    float hx = (float)h[0], hy = (float)h[1], hz = (float)h[2], hw = (float)h[3];
    float ps = hx * s4.x + hy * s4.y + hz * s4.z + hw * s4.w;
    float pd = hx * d4.x + hy * d4.y + hz * d4.z + hw * d4.w;
    for (int off = 1; off < 16; off <<= 1) { ps += __shfl_xor(ps, off); pd += __shfl_xor(pd, off); }
    if ((lane & 15) == 0) {
        int hh = lane >> 4;
        es[n * 4 + hh] = ps;
        ed[n * 4 + hh] = pd;
    }
}

__global__ __launch_bounds__(256) void scores_ms_kernel(const f16* __restrict__ H, const float* __restrict__ aS,
                                                        const float* __restrict__ aD, float* __restrict__ es,
                                                        float* __restrict__ ed) {
    int wave = threadIdx.x >> 6, lane = threadIdx.x & 63;
    int n = blockIdx.x * 4 + wave;
    if (n >= NN) return;
    float h = (float)H[(size_t)n * 64 + lane];
    float ps = h * aS[lane];
    float pd = h * aD[lane];
    for (int off = 1; off < 32; off <<= 1) { ps += __shfl_xor(ps, off); pd += __shfl_xor(pd, off); }
    if ((lane & 31) == 0) {
        int g = lane >> 5;
        es[n * 2 + g] = ps;
        ed[n * 2 + g] = pd;
    }
}

__device__ __forceinline__ float leaky(float v) { return v > 0.f ? v : NEG_SLOPE * v; }

// ---------------- softmax alpha (CSR order) for the 4-head layers ----------------

__device__ __forceinline__ void softmax4(
    int n, int lane, const float* __restrict__ es, const float* __restrict__ ed,
    const int* __restrict__ offs, const int* __restrict__ csrc, const int* __restrict__ ceid,
    float* __restrict__ etmp, float* __restrict__ alpha_out, int start, int deg) {
    int h = lane >> 4, sub = lane & 15;
    float edh = ed[n * 4 + h];
    float m = -INFINITY;
    for (int j = sub; j < deg; j += 16) {
        int s = csrc[start + j];
        float v = leaky(es[s * 4 + h] + edh);
        etmp[(size_t)(start + j) * 4 + h] = v;
        m = fmaxf(m, v);
    }
    for (int off = 1; off < 16; off <<= 1) m = fmaxf(m, __shfl_xor(m, off));
    float dsum = 0.f;
    for (int j = sub; j < deg; j += 16) {
        float t = __expf(etmp[(size_t)(start + j) * 4 + h] - m);
        etmp[(size_t)(start + j) * 4 + h] = t;
        dsum += t;
    }
    for (int off = 1; off < 16; off <<= 1) dsum += __shfl_xor(dsum, off);
    float inv = 1.f / (dsum + 1e-16f);
    for (int j = sub; j < deg; j += 16) {
        float a = etmp[(size_t)(start + j) * 4 + h] * inv;
        etmp[(size_t)(start + j) * 4 + h] = a;
        alpha_out[(size_t)ceid[start + j] * 4 + h] = a;
    }
}

// ---------------- layer-1 aggregation (concat heads, +bias, relu, f16 out) ----------------
__global__ __launch_bounds__(256) void agg_concat_kernel(
    const f16* __restrict__ H, const float* __restrict__ es, const float* __restrict__ ed,
    const int* __restrict__ offs, const int* __restrict__ csrc, const int* __restrict__ ceid,
    const float* __restrict__ bias, f16* __restrict__ out, float* __restrict__ alpha_out,
    float* __restrict__ etmp) {
    int wave = threadIdx.x >> 6, lane = threadIdx.x & 63;
    int n = blockIdx.x * 4 + wave;
    if (n >= NN) return;
    int h = lane >> 4;
    int start = offs[n];
    int end = (n + 1 < NN) ? offs[n + 1] : ETOT;
    int deg = end - start;
    softmax4(n, lane, es, ed, offs, csrc, ceid, etmp, alpha_out, start, deg);
    int cbase = lane * 4;
    float4 acc0 = {}, acc1 = {}, acc2 = {}, acc3 = {};
    int j = 0;
    for (; j + 3 < deg; j += 4) {
        int p = start + j;
        int s0 = csrc[p], s1 = csrc[p + 1], s2 = csrc[p + 2], s3 = csrc[p + 3];
        float a0 = etmp[(size_t)p * 4 + h];
        float a1 = etmp[(size_t)(p + 1) * 4 + h];
        float a2 = etmp[(size_t)(p + 2) * 4 + h];
        float a3 = etmp[(size_t)(p + 3) * 4 + h];
        f16x4 v0 = *(const f16x4*)(H + (size_t)s0 * 256 + cbase);
        f16x4 v1 = *(const f16x4*)(H + (size_t)s1 * 256 + cbase);
        f16x4 v2 = *(const f16x4*)(H + (size_t)s2 * 256 + cbase);
        f16x4 v3 = *(const f16x4*)(H + (size_t)s3 * 256 + cbase);
        acc0.x += a0 * (float)v0[0]; acc0.y += a0 * (float)v0[1]; acc0.z += a0 * (float)v0[2]; acc0.w += a0 * (float)v0[3];
        acc1.x += a1 * (float)v1[0]; acc1.y += a1 * (float)v1[1]; acc1.z += a1 * (float)v1[2]; acc1.w += a1 * (float)v1[3];
        acc2.x += a2 * (float)v2[0]; acc2.y += a2 * (float)v2[1]; acc2.z += a2 * (float)v2[2]; acc2.w += a2 * (float)v2[3];
        acc3.x += a3 * (float)v3[0]; acc3.y += a3 * (float)v3[1]; acc3.z += a3 * (float)v3[2]; acc3.w += a3 * (float)v3[3];
    }
    for (; j < deg; ++j) {
        int p = start + j;
        int s0 = csrc[p];
        float a0 = etmp[(size_t)p * 4 + h];
        f16x4 v0 = *(const f16x4*)(H + (size_t)s0 * 256 + cbase);
        acc0.x += a0 * (float)v0[0]; acc0.y += a0 * (float)v0[1]; acc0.z += a0 * (float)v0[2]; acc0.w += a0 * (float)v0[3];
    }
    float4 acc;
    acc.x = (acc0.x + acc1.x) + (acc2.x + acc3.x);
    acc.y = (acc0.y + acc1.y) + (acc2.y + acc3.y);
    acc.z = (acc0.z + acc1.z) + (acc2.z + acc3.z);
    acc.w = (acc0.w + acc1.w) + (acc2.w + acc3.w);
    float4 b = *(const float4*)(bias + cbase);
    f16x4 r;
    r[0] = (f16)fmaxf(acc.x + b.x, 0.f);
    r[1] = (f16)fmaxf(acc.y + b.y, 0.f);
    r[2] = (f16)fmaxf(acc.z + b.z, 0.f);
    r[3] = (f16)fmaxf(acc.w + b.w, 0.f);
    *(f16x4*)(out + (size_t)n * 256 + cbase) = r;
}

// ---------------- layer-2 aggregation (mean over 4 heads, +bias, relu, f16 out) ----------------
__global__ __launch_bounds__(256) void agg_mean_kernel(
    const f16* __restrict__ H, const float* __restrict__ es, const float* __restrict__ ed,
    const int* __restrict__ offs, const int* __restrict__ csrc, const int* __restrict__ ceid,
    const float* __restrict__ bias, f16* __restrict__ out, float* __restrict__ alpha_out,
    float* __restrict__ etmp) {
    int wave = threadIdx.x >> 6, lane = threadIdx.x & 63;
    int n = blockIdx.x * 4 + wave;
    if (n >= NN) return;
    int h = lane >> 4;
    int start = offs[n];
    int end = (n + 1 < NN) ? offs[n + 1] : ETOT;
    int deg = end - start;
    softmax4(n, lane, es, ed, offs, csrc, ceid, etmp, alpha_out, start, deg);
    int cbase = lane * 4;
    float4 acc0 = {}, acc1 = {}, acc2 = {}, acc3 = {};
    int j = 0;
    for (; j + 3 < deg; j += 4) {
        int p = start + j;
        int s0 = csrc[p], s1 = csrc[p + 1], s2 = csrc[p + 2], s3 = csrc[p + 3];
        float a0 = etmp[(size_t)p * 4 + h];
        float a1 = etmp[(size_t)(p + 1) * 4 + h];
        float a2 = etmp[(size_t)(p + 2) * 4 + h];
        float a3 = etmp[(size_t)(p + 3) * 4 + h];
        f16x4 v0 = *(const f16x4*)(H + (size_t)s0 * 256 + cbase);
        f16x4 v1 = *(const f16x4*)(H + (size_t)s1 * 256 + cbase);
        f16x4 v2 = *(const f16x4*)(H + (size_t)s2 * 256 + cbase);
        f16x4 v3 = *(const f16x4*)(H + (size_t)s3 * 256 + cbase);
        acc0.x += a0 * (float)v0[0]; acc0.y += a0 * (float)v0[1]; acc0.z += a0 * (float)v0[2]; acc0.w += a0 * (float)v0[3];
        acc1.x += a1 * (float)v1[0]; acc1.y += a1 * (float)v1[1]; acc1.z += a1 * (float)v1[2]; acc1.w += a1 * (float)v1[3];
        acc2.x += a2 * (float)v2[0]; acc2.y += a2 * (float)v2[1]; acc2.z += a2 * (float)v2[2]; acc2.w += a2 * (float)v2[3];
        acc3.x += a3 * (float)v3[0]; acc3.y += a3 * (float)v3[1]; acc3.z += a3 * (float)v3[2]; acc3.w += a3 * (float)v3[3];
    }
    for (; j < deg; ++j) {
        int p = start + j;
        int s0 = csrc[p];
        float a0 = etmp[(size_t)p * 4 + h];
        f16x4 v0 = *(const f16x4*)(H + (size_t)s0 * 256 + cbase);
        acc0.x += a0 * (float)v0[0]; acc0.y += a0 * (float)v0[1]; acc0.z += a0 * (float)v0[2]; acc0.w += a0 * (float)v0[3];
    }
    float4 acc;
    acc.x = (acc0.x + acc1.x) + (acc2.x + acc3.x);
    acc.y = (acc0.y + acc1.y) + (acc2.y + acc3.y);
    acc.z = (acc0.z + acc1.z) + (acc2.z + acc3.z);
    acc.w = (acc0.w + acc1.w) + (acc2.w + acc3.w);
    // sum across the 4 heads (lanes l, l^16, l^32, l^48 hold same channel)
    acc.x += __shfl_xor(acc.x, 16); acc.y += __shfl_xor(acc.y, 16);
    acc.z += __shfl_xor(acc.z, 16); acc.w += __shfl_xor(acc.w, 16);
    acc.x += __shfl_xor(acc.x, 32); acc.y += __shfl_xor(acc.y, 32);
    acc.z += __shfl_xor(acc.z, 32); acc.w += __shfl_xor(acc.w, 32);
    if (lane < 16) {
        float4 b = *(const float4*)(bias + lane * 4);
        f16x4 r;
        r[0] = (f16)fmaxf(acc.x * 0.25f + b.x, 0.f);
        r[1] = (f16)fmaxf(acc.y * 0.25f + b.y, 0.f);
        r[2] = (f16)fmaxf(acc.z * 0.25f + b.z, 0.f);
        r[3] = (f16)fmaxf(acc.w * 0.25f + b.w, 0.f);
        *(f16x4*)(out + (size_t)n * 64 + lane * 4) = r;
    }
}

// ---------------- mean/log_std heads aggregation (2 pseudo-heads of 32 ch) ----------------
__global__ __launch_bounds__(256) void agg_ms_kernel(
    const f16* __restrict__ H, const float* __restrict__ es, const float* __restrict__ ed,
    const int* __restrict__ offs, const int* __restrict__ csrc, const int* __restrict__ ceid,
    const float* __restrict__ bm, const float* __restrict__ bs,
    float* __restrict__ zmean, float* __restrict__ zlog,
    float* __restrict__ a_wm, float* __restrict__ a_ws,
    float* __restrict__ etmp) {
    int wave = threadIdx.x >> 6, lane = threadIdx.x & 63;
    int n = blockIdx.x * 4 + wave;
    if (n >= NN) return;
    int g = lane >> 5, sub = lane & 31;
    int start = offs[n];
    int end = (n + 1 < NN) ? offs[n + 1] : ETOT;
    int deg = end - start;
    float edh = ed[n * 2 + g];
    float m = -INFINITY;
    for (int j = sub; j < deg; j += 32) {
        int s = csrc[start + j];
        float v = leaky(es[s * 2 + g] + edh);
        etmp[(size_t)(start + j) * 2 + g] = v;
        m = fmaxf(m, v);
    }
    for (int off = 1; off < 32; off <<= 1) m = fmaxf(m, __shfl_xor(m, off));
    float dsum = 0.f;
    for (int j = sub; j < deg; j += 32) {
        float t = __expf(etmp[(size_t)(start + j) * 2 + g] - m);
        etmp[(size_t)(start + j) * 2 + g] = t;
        dsum += t;
    }
    for (int off = 1; off < 32; off <<= 1) dsum += __shfl_xor(dsum, off);
    float inv = 1.f / (dsum + 1e-16f);
    for (int j = sub; j < deg; j += 32) {
        float a = etmp[(size_t)(start + j) * 2 + g] * inv;
        etmp[(size_t)(start + j) * 2 + g] = a;
        int eid = ceid[start + j];
        if (g == 0) a_wm[eid] = a; else a_ws[eid] = a;
    }
    float acc0 = 0.f, acc1 = 0.f, acc2 = 0.f, acc3 = 0.f;
    int j = 0;
    for (; j + 3 < deg; j += 4) {
        int p = start + j;
        int s0 = csrc[p], s1 = csrc[p + 1], s2 = csrc[p + 2], s3 = csrc[p + 3];
        float a0 = etmp[(size_t)p * 2 + g];
        float a1 = etmp[(size_t)(p + 1) * 2 + g];
        float a2 = etmp[(size_t)(p + 2) * 2 + g];
        float a3 = etmp[(size_t)(p + 3) * 2 + g];
        acc0 += a0 * (float)H[(size_t)s0 * 64 + lane];
        acc1 += a1 * (float)H[(size_t)s1 * 64 + lane];
        acc2 += a2 * (float)H[(size_t)s2 * 64 + lane];
        acc3 += a3 * (float)H[(size_t)s3 * 64 + lane];
    }
    for (; j < deg; ++j) {
        int p = start + j;
        int s0 = csrc[p];
        float a0 = etmp[(size_t)p * 2 + g];
        acc0 += a0 * (float)H[(size_t)s0 * 64 + lane];
    }
    float acc = (acc0 + acc1) + (acc2 + acc3);
    if (g == 0) zmean[(size_t)n * 32 + sub] = acc + bm[sub];
    else        zlog[(size_t)n * 32 + sub] = acc + bs[sub];
}

// ---------------- launch ----------------

extern "C" void kernel_launch(void* const* d_in, const int* in_sizes, int n_in,
                              void* d_out, int out_size, void* d_ws, size_t ws_size,
                              hipStream_t stream) {
    const float* x   = (const float*)d_in[0];
    const int*   ei  = (const int*)d_in[1];
    const float* W1  = (const float*)d_in[2];
    const float* a1s = (const float*)d_in[3];
    const float* a1d = (const float*)d_in[4];
    const float* b1  = (const float*)d_in[5];
    const float* W2  = (const float*)d_in[6];
    const float* a2s = (const float*)d_in[7];
    const float* a2d = (const float*)d_in[8];
    const float* b2  = (const float*)d_in[9];
    const float* Wm  = (const float*)d_in[10];
    const float* ams = (const float*)d_in[11];
    const float* amd = (const float*)d_in[12];
    const float* bm  = (const float*)d_in[13];
    const float* Ws  = (const float*)d_in[14];
    const float* ass = (const float*)d_in[15];
    const float* asd = (const float*)d_in[16];
    const float* bs  = (const float*)d_in[17];

    float* out = (float*)d_out;
    float* zmean = out;                       // [50000,32]
    float* zlog  = out + 1600000;             // [50000,32]
    float* a_w1  = out + 3200000;             // [850000,4]
    float* a_w2  = out + 6600000;             // [850000,4]
    float* a_wm  = out + 10000000;            // [850000]
    float* a_ws_o = out + 10850000;           // [850000]

    float* ws = (float*)d_ws;
    size_t o = 0;
    f16*   Hh   = (f16*)(ws + o); o += (size_t)NN * 128;  // GEMM out [NN,256] f16, reused each layer
    f16*   h1h  = (f16*)(ws + o); o += (size_t)NN * 128;  // relu(h1) f16 (GEMM2 A)
    f16*   h2h  = (f16*)(ws + o); o += (size_t)NN * 32;   // h2 f16 [NN,64] (GEMM3 A)
    float* etmp = ws + o; o += (size_t)ETOT * 4;   // CSR-order scores/alpha scratch
    float* es1  = ws + o; o += NN * 4;
    float* ed1  = ws + o; o += NN * 4;
    float* es2  = ws + o; o += NN * 4;
    float* ed2  = ws + o; o += NN * 4;
    float* esms = ws + o; o += NN * 2;
    float* edms = ws + o; o += NN * 2;
    f16*   Wt1  = (f16*)(ws + o); o += 32768;      // [256][256] f16 transposed
    f16*   Wt2  = (f16*)(ws + o); o += 32768;
    f16*   Wtms = (f16*)(ws + o); o += 2048;       // [64][64] f16 transposed
    float* aSms = ws + o; o += 64;
    float* aDms = ws + o; o += 64;
    int* deg    = (int*)(ws + o); o += NN;
    int* offs   = (int*)(ws + o); o += NN;
    int* cursor = (int*)(ws + o); o += NN;
    int* csrc   = (int*)(ws + o); o += ETOT;
    int* ceid   = (int*)(ws + o); o += ETOT;

    const int edgeBlocks = (ETOT + 255) / 256;   // 3321
    const int nodeBlocks = (NN + 255) / 256;     // 196
    const int waveBlocks = (NN + 3) / 4;         // 12500

    // ---- CSR build ----
    hipMemsetAsync(deg, 0, NN * sizeof(int), stream);
    deg_kernel<<<edgeBlocks, 256, 0, stream>>>(ei, deg);
    scan1_kernel<<<nodeBlocks, 256, 0, stream>>>(deg, offs, cursor /*tmp bsum*/, NN);
    scan2_kernel<<<1, 256, 0, stream>>>(cursor, nodeBlocks);
    scan3_kernel<<<nodeBlocks, 256, 0, stream>>>(cursor, offs, deg /*reuse as cursor*/, NN);
    fill_kernel<<<edgeBlocks, 256, 0, stream>>>(ei, deg, csrc, ceid);

    // ---- pack weights (f16 + transpose) ----
    packw_kernel<<<256, 256, 0, stream>>>(W1, W2, Wm, Ws, ams, ass, amd, asd, Wt1, Wt2, Wtms, aSms, aDms);

    dim3 gg1(4, (NN + 127) / 128);   // N=256 / BN=64, M tiles of 128
    dim3 gg3(1, (NN + 127) / 128);   // N=64
    // ---- layer 1 ----
    mfma_gemm<256, true><<<gg1, 256, 0, stream>>>(x, Wt1, Hh, NN, 256);
    scores4_kernel<<<waveBlocks, 256, 0, stream>>>(Hh, a1s, a1d, es1, ed1);
    agg_concat_kernel<<<waveBlocks, 256, 0, stream>>>(Hh, es1, ed1, offs, csrc, ceid, b1, h1h, a_w1, etmp);

    // ---- layer 2 ----
    mfma_gemm<256, false><<<gg1, 256, 0, stream>>>(h1h, Wt2, Hh, NN, 256);
    scores4_kernel<<<waveBlocks, 256, 0, stream>>>(Hh, a2s, a2d, es2, ed2);
    agg_mean_kernel<<<waveBlocks, 256, 0, stream>>>(Hh, es2, ed2, offs, csrc, ceid, b2, h2h, a_w2, etmp);

    // ---- mean / log_std heads ----
    mfma_gemm<64, false><<<gg3, 256, 0, stream>>>(h2h, Wtms, Hh, NN, 64);
    scores_ms_kernel<<<waveBlocks, 256, 0, stream>>>(Hh, aSms, aDms, esms, edms);
    agg_ms_kernel<<<waveBlocks, 256, 0, stream>>>(Hh, esms, edms, offs, csrc, ceid, bm, bs,
                                                  zmean, zlog, a_wm, a_ws_o, etmp);
}

// Round 3
// 546.610 us; speedup vs baseline: 1.4641x; 1.0421x over previous
//
#include <hip/hip_runtime.h>
#include <cstdint>
#include <cstddef>

#define NN 50000
#define EE 800000
#define ETOT 850000   // EE + NN self loops
#define NEG_SLOPE 0.2f

typedef _Float16 f16;
typedef __attribute__((ext_vector_type(4))) _Float16 f16x4;
typedef __attribute__((ext_vector_type(8))) _Float16 f16x8;
typedef __attribute__((ext_vector_type(4))) float f32x4;

// ---------------- CSR build ----------------

__global__ __launch_bounds__(256) void deg_kernel(const int* __restrict__ ei, int* __restrict__ deg) {
    int e = blockIdx.x * 256 + threadIdx.x;
    if (e >= ETOT) return;
    int d = (e < EE) ? ei[EE + e] : (e - EE);
    atomicAdd(&deg[d], 1);
}

__global__ __launch_bounds__(256) void scan1_kernel(const int* __restrict__ deg, int* __restrict__ offs,
                                                    int* __restrict__ bsum, int n) {
    __shared__ int sh[256];
    int i = blockIdx.x * 256 + threadIdx.x;
    int v = (i < n) ? deg[i] : 0;
    sh[threadIdx.x] = v;
    __syncthreads();
    for (int off = 1; off < 256; off <<= 1) {
        int t = (threadIdx.x >= off) ? sh[threadIdx.x - off] : 0;
        __syncthreads();
        sh[threadIdx.x] += t;
        __syncthreads();
    }
    if (i < n) offs[i] = sh[threadIdx.x] - v;   // exclusive within block
    if (threadIdx.x == 255) bsum[blockIdx.x] = sh[255];
}

__global__ __launch_bounds__(256) void scan2_kernel(int* __restrict__ bsum, int nb) {
    __shared__ int sh[256];
    int v = (threadIdx.x < nb) ? bsum[threadIdx.x] : 0;
    sh[threadIdx.x] = v;
    __syncthreads();
    for (int off = 1; off < 256; off <<= 1) {
        int t = (threadIdx.x >= off) ? sh[threadIdx.x - off] : 0;
        __syncthreads();
        sh[threadIdx.x] += t;
        __syncthreads();
    }
    if (threadIdx.x < nb) bsum[threadIdx.x] = sh[threadIdx.x] - v;  // exclusive
}

__global__ __launch_bounds__(256) void scan3_kernel(const int* __restrict__ bsum, int* __restrict__ offs,
                                                    int* __restrict__ cursor, int n) {
    int i = blockIdx.x * 256 + threadIdx.x;
    if (i < n) {
        int o = offs[i] + bsum[blockIdx.x];
        offs[i] = o;
        cursor[i] = o;
    }
}

__global__ __launch_bounds__(256) void fill_kernel(const int* __restrict__ ei, int* __restrict__ cursor,
                                                   int* __restrict__ csrc, int* __restrict__ ceid) {
    int e = blockIdx.x * 256 + threadIdx.x;
    if (e >= ETOT) return;
    int d, s;
    if (e < EE) { s = ei[e]; d = ei[EE + e]; } else { s = e - EE; d = e - EE; }
    int p = atomicAdd(&cursor[d], 1);
    csrc[p] = s;
    ceid[p] = e;
}

// ---------------- MFMA GEMM: A[MxK] (f32 or f16) * Wt[N][K]^T -> C f16 [MxN] ----------------

template<int K, bool AF32>
__global__ __launch_bounds__(256) void mfma_gemm(const void* __restrict__ Ap, const f16* __restrict__ Bt,
                                                 f16* __restrict__ C, int M, int N) {
    int w = threadIdx.x >> 6, lane = threadIdx.x & 63;
    int m0 = blockIdx.y * 128 + w * 32;
    int n0 = blockIdx.x * 64;
    int r = lane & 15, kb = lane >> 4;
    int ar0 = m0 + r;       if (ar0 > M - 1) ar0 = M - 1;
    int ar1 = m0 + 16 + r;  if (ar1 > M - 1) ar1 = M - 1;
    f32x4 acc[2][4] = {};
    const float* Af = (const float*)Ap;
    const f16*   Ah = (const f16*)Ap;
    size_t a0off = (size_t)ar0 * K + kb * 8;
    size_t a1off = (size_t)ar1 * K + kb * 8;
    const f16* bbase = Bt + (size_t)(n0 + r) * K + kb * 8;
    for (int k0 = 0; k0 < K; k0 += 32) {
        f16x8 a0, a1;
        if constexpr (AF32) {
            float4 l0 = *(const float4*)(Af + a0off + k0);
            float4 h0 = *(const float4*)(Af + a0off + k0 + 4);
            float4 l1 = *(const float4*)(Af + a1off + k0);
            float4 h1 = *(const float4*)(Af + a1off + k0 + 4);
            a0[0]=(f16)l0.x; a0[1]=(f16)l0.y; a0[2]=(f16)l0.z; a0[3]=(f16)l0.w;
            a0[4]=(f16)h0.x; a0[5]=(f16)h0.y; a0[6]=(f16)h0.z; a0[7]=(f16)h0.w;
            a1[0]=(f16)l1.x; a1[1]=(f16)l1.y; a1[2]=(f16)l1.z; a1[3]=(f16)l1.w;
            a1[4]=(f16)h1.x; a1[5]=(f16)h1.y; a1[6]=(f16)h1.z; a1[7]=(f16)h1.w;
        } else {
            a0 = *(const f16x8*)(Ah + a0off + k0);
            a1 = *(const f16x8*)(Ah + a1off + k0);
        }
#pragma unroll
        for (int ni = 0; ni < 4; ++ni) {
            f16x8 b = *(const f16x8*)(bbase + (size_t)ni * 16 * K + k0);
            acc[0][ni] = __builtin_amdgcn_mfma_f32_16x16x32_f16(a0, b, acc[0][ni], 0, 0, 0);
            acc[1][ni] = __builtin_amdgcn_mfma_f32_16x16x32_f16(a1, b, acc[1][ni], 0, 0, 0);
        }
    }
#pragma unroll
    for (int mi = 0; mi < 2; ++mi) {
#pragma unroll
        for (int i = 0; i < 4; ++i) {
            int row = m0 + mi * 16 + kb * 4 + i;
            if (row < M) {
#pragma unroll
                for (int ni = 0; ni < 4; ++ni)
                    C[(size_t)row * N + n0 + ni * 16 + r] = (f16)acc[mi][ni][i];
            }
        }
    }
}

// ---------------- pack weights: f16 + transpose (Wt[N][K]) ----------------

__global__ __launch_bounds__(256) void packw_kernel(const float* __restrict__ W1, const float* __restrict__ W2,
                                                    const float* __restrict__ Wm, const float* __restrict__ Ws,
                                                    const float* __restrict__ ams, const float* __restrict__ ass,
                                                    const float* __restrict__ amd, const float* __restrict__ asd,
                                                    f16* __restrict__ Wt1, f16* __restrict__ Wt2,
                                                    f16* __restrict__ Wtms,
                                                    float* __restrict__ aS, float* __restrict__ aD) {
    int i = blockIdx.x * 256 + threadIdx.x;
    if (i < 65536) {
        int n = i >> 8, k = i & 255;   // Wt[n][k] = W[k][n]
        Wt1[(size_t)n * 256 + k] = (f16)W1[(size_t)k * 256 + n];
        Wt2[(size_t)n * 256 + k] = (f16)W2[(size_t)k * 256 + n];
    }
    if (i < 4096) {
        int c = i >> 6, k = i & 63;    // Wtms[c][k]: c<32 -> Wm[k][c], else Ws[k][c-32]
        float v = (c < 32) ? Wm[k * 32 + c] : Ws[k * 32 + (c - 32)];
        Wtms[(size_t)c * 64 + k] = (f16)v;
    }
    if (i < 64) {
        aS[i] = (i < 32) ? ams[i] : ass[i - 32];
        aD[i] = (i < 32) ? amd[i] : asd[i - 32];
    }
}

// ---------------- attention score dots (fp16 H) ----------------

__global__ __launch_bounds__(256) void scores4_kernel(const f16* __restrict__ H, const float* __restrict__ aS,
                                                      const float* __restrict__ aD, float* __restrict__ es,
                                                      float* __restrict__ ed) {
    int wave = threadIdx.x >> 6, lane = threadIdx.x & 63;
    int n = blockIdx.x * 4 + wave;
    if (n >= NN) return;
    f16x4 h = *(const f16x4*)(H + (size_t)n * 256 + lane * 4);
    float4 s4 = *(const float4*)(aS + lane * 4);
    float4 d4 = *(const float4*)(aD + lane * 4);
    float hx = (float)h[0], hy = (float)h[1], hz = (float)h[2], hw = (float)h[3];
    float ps = hx * s4.x + hy * s4.y + hz * s4.z + hw * s4.w;
    float pd = hx * d4.x + hy * d4.y + hz * d4.z + hw * d4.w;
    for (int off = 1; off < 16; off <<= 1) { ps += __shfl_xor(ps, off); pd += __shfl_xor(pd, off); }
    if ((lane & 15) == 0) {
        int hh = lane >> 4;
        es[n * 4 + hh] = ps;
        ed[n * 4 + hh] = pd;
    }
}

__global__ __launch_bounds__(256) void scores_ms_kernel(const f16* __restrict__ H, const float* __restrict__ aS,
                                                        const float* __restrict__ aD, float* __restrict__ es,
                                                        float* __restrict__ ed) {
    int wave = threadIdx.x >> 6, lane = threadIdx.x & 63;
    int n = blockIdx.x * 4 + wave;
    if (n >= NN) return;
    float h = (float)H[(size_t)n * 64 + lane];
    float ps = h * aS[lane];
    float pd = h * aD[lane];
    for (int off = 1; off < 32; off <<= 1) { ps += __shfl_xor(ps, off); pd += __shfl_xor(pd, off); }
    if ((lane & 31) == 0) {
        int g = lane >> 5;
        es[n * 2 + g] = ps;
        ed[n * 2 + g] = pd;
    }
}

__device__ __forceinline__ float leaky(float v) { return v > 0.f ? v : NEG_SLOPE * v; }

// ---------------- layer-1 aggregation: online softmax (no scratch), 16B gathers ----------------
// Pass 1: denominator per head (no max-sub; |e| <= ~12 so exp is safe in fp32).
// Pass 2: 2 edges/wave-iter, 8 f16 ch/lane; alpha recomputed on the fly; alpha_out from 1 lane/(edge,head).

__global__ __launch_bounds__(256) void agg_concat_kernel(
    const f16* __restrict__ H, const float* __restrict__ es, const float* __restrict__ ed,
    const int* __restrict__ offs, const int* __restrict__ csrc, const int* __restrict__ ceid,
    const float* __restrict__ bias, f16* __restrict__ out, float* __restrict__ alpha_out) {
    int wave = threadIdx.x >> 6, lane = threadIdx.x & 63;
    int n = blockIdx.x * 4 + wave;
    if (n >= NN) return;
    int start = offs[n];
    int end = (n + 1 < NN) ? offs[n + 1] : ETOT;
    int deg = end - start;
    // ---- pass 1: denominators ----
    int h16 = lane >> 4, sub = lane & 15;
    float edh = ed[n * 4 + h16];
    float dsum = 0.f;
    for (int j = sub; j < deg; j += 16) {
        int s = csrc[start + j];
        dsum += __expf(leaky(es[s * 4 + h16] + edh));
    }
    for (int off = 1; off < 16; off <<= 1) dsum += __shfl_xor(dsum, off);
    float inv = 1.f / (dsum + 1e-16f);
    // ---- pass 2: aggregate ----
    int half = lane >> 5;          // edge slot (2 edges per iteration)
    int l5 = lane & 31;
    int hh = l5 >> 3;              // head owning channels c8..c8+7
    int c8 = l5 * 8;
    float invh = __shfl(inv, hh << 4);
    float edhh = __shfl(edh, hh << 4);
    bool writer = ((l5 & 7) == 0);
    float accv[8] = {};
    int j = half;
    for (; j + 6 < deg; j += 8) {
        int p0 = start + j, p1 = start + j + 2, p2 = start + j + 4, p3 = start + j + 6;
        int s0 = csrc[p0], s1 = csrc[p1], s2 = csrc[p2], s3 = csrc[p3];
        float a0 = __expf(leaky(es[s0 * 4 + hh] + edhh)) * invh;
        float a1 = __expf(leaky(es[s1 * 4 + hh] + edhh)) * invh;
        float a2 = __expf(leaky(es[s2 * 4 + hh] + edhh)) * invh;
        float a3 = __expf(leaky(es[s3 * 4 + hh] + edhh)) * invh;
        if (writer) {
            alpha_out[(size_t)ceid[p0] * 4 + hh] = a0;
            alpha_out[(size_t)ceid[p1] * 4 + hh] = a1;
            alpha_out[(size_t)ceid[p2] * 4 + hh] = a2;
            alpha_out[(size_t)ceid[p3] * 4 + hh] = a3;
        }
        f16x8 v0 = *(const f16x8*)(H + (size_t)s0 * 256 + c8);
        f16x8 v1 = *(const f16x8*)(H + (size_t)s1 * 256 + c8);
        f16x8 v2 = *(const f16x8*)(H + (size_t)s2 * 256 + c8);
        f16x8 v3 = *(const f16x8*)(H + (size_t)s3 * 256 + c8);
#pragma unroll
        for (int k = 0; k < 8; ++k)
            accv[k] += a0 * (float)v0[k] + a1 * (float)v1[k] + a2 * (float)v2[k] + a3 * (float)v3[k];
    }
    for (; j < deg; j += 2) {
        int p0 = start + j;
        int s0 = csrc[p0];
        float a0 = __expf(leaky(es[s0 * 4 + hh] + edhh)) * invh;
        if (writer) alpha_out[(size_t)ceid[p0] * 4 + hh] = a0;
        f16x8 v0 = *(const f16x8*)(H + (size_t)s0 * 256 + c8);
#pragma unroll
        for (int k = 0; k < 8; ++k) accv[k] += a0 * (float)v0[k];
    }
#pragma unroll
    for (int k = 0; k < 8; ++k) accv[k] += __shfl_xor(accv[k], 32);
    if (lane < 32) {
        f16x8 r;
#pragma unroll
        for (int k = 0; k < 8; ++k) r[k] = (f16)fmaxf(accv[k] + bias[c8 + k], 0.f);
        *(f16x8*)(out + (size_t)n * 256 + c8) = r;
    }
}

// ---------------- layer-2 aggregation (mean over 4 heads), same structure ----------------

__global__ __launch_bounds__(256) void agg_mean_kernel(
    const f16* __restrict__ H, const float* __restrict__ es, const float* __restrict__ ed,
    const int* __restrict__ offs, const int* __restrict__ csrc, const int* __restrict__ ceid,
    const float* __restrict__ bias, f16* __restrict__ out, float* __restrict__ alpha_out) {
    int wave = threadIdx.x >> 6, lane = threadIdx.x & 63;
    int n = blockIdx.x * 4 + wave;
    if (n >= NN) return;
    int start = offs[n];
    int end = (n + 1 < NN) ? offs[n + 1] : ETOT;
    int deg = end - start;
    int h16 = lane >> 4, sub = lane & 15;
    float edh = ed[n * 4 + h16];
    float dsum = 0.f;
    for (int j = sub; j < deg; j += 16) {
        int s = csrc[start + j];
        dsum += __expf(leaky(es[s * 4 + h16] + edh));
    }
    for (int off = 1; off < 16; off <<= 1) dsum += __shfl_xor(dsum, off);
    float inv = 1.f / (dsum + 1e-16f);
    int half = lane >> 5;
    int l5 = lane & 31;
    int hh = l5 >> 3;
    int c8 = l5 * 8;
    float invh = __shfl(inv, hh << 4);
    float edhh = __shfl(edh, hh << 4);
    bool writer = ((l5 & 7) == 0);
    float accv[8] = {};
    int j = half;
    for (; j + 6 < deg; j += 8) {
        int p0 = start + j, p1 = start + j + 2, p2 = start + j + 4, p3 = start + j + 6;
        int s0 = csrc[p0], s1 = csrc[p1], s2 = csrc[p2], s3 = csrc[p3];
        float a0 = __expf(leaky(es[s0 * 4 + hh] + edhh)) * invh;
        float a1 = __expf(leaky(es[s1 * 4 + hh] + edhh)) * invh;
        float a2 = __expf(leaky(es[s2 * 4 + hh] + edhh)) * invh;
        float a3 = __expf(leaky(es[s3 * 4 + hh] + edhh)) * invh;
        if (writer) {
            alpha_out[(size_t)ceid[p0] * 4 + hh] = a0;
            alpha_out[(size_t)ceid[p1] * 4 + hh] = a1;
            alpha_out[(size_t)ceid[p2] * 4 + hh] = a2;
            alpha_out[(size_t)ceid[p3] * 4 + hh] = a3;
        }
        f16x8 v0 = *(const f16x8*)(H + (size_t)s0 * 256 + c8);
        f16x8 v1 = *(const f16x8*)(H + (size_t)s1 * 256 + c8);
        f16x8 v2 = *(const f16x8*)(H + (size_t)s2 * 256 + c8);
        f16x8 v3 = *(const f16x8*)(H + (size_t)s3 * 256 + c8);
#pragma unroll
        for (int k = 0; k < 8; ++k)
            accv[k] += a0 * (float)v0[k] + a1 * (float)v1[k] + a2 * (float)v2[k] + a3 * (float)v3[k];
    }
    for (; j < deg; j += 2) {
        int p0 = start + j;
        int s0 = csrc[p0];
        float a0 = __expf(leaky(es[s0 * 4 + hh] + edhh)) * invh;
        if (writer) alpha_out[(size_t)ceid[p0] * 4 + hh] = a0;
        f16x8 v0 = *(const f16x8*)(H + (size_t)s0 * 256 + c8);
#pragma unroll
        for (int k = 0; k < 8; ++k) accv[k] += a0 * (float)v0[k];
    }
    // reduce over heads (lane bits 3,4) and edge-half (bit 5)
#pragma unroll
    for (int k = 0; k < 8; ++k) {
        accv[k] += __shfl_xor(accv[k], 8);
        accv[k] += __shfl_xor(accv[k], 16);
        accv[k] += __shfl_xor(accv[k], 32);
    }
    if (lane < 8) {
        f16x8 r;
#pragma unroll
        for (int k = 0; k < 8; ++k) r[k] = (f16)fmaxf(accv[k] * 0.25f + bias[lane * 8 + k], 0.f);
        *(f16x8*)(out + (size_t)n * 64 + lane * 8) = r;
    }
}

// ---------------- mean/log_std heads aggregation: 8 edges/iter, 16B gathers ----------------

__global__ __launch_bounds__(256) void agg_ms_kernel(
    const f16* __restrict__ H, const float* __restrict__ es, const float* __restrict__ ed,
    const int* __restrict__ offs, const int* __restrict__ csrc, const int* __restrict__ ceid,
    const float* __restrict__ bm, const float* __restrict__ bs,
    float* __restrict__ zmean, float* __restrict__ zlog,
    float* __restrict__ a_wm, float* __restrict__ a_ws) {
    int wave = threadIdx.x >> 6, lane = threadIdx.x & 63;
    int n = blockIdx.x * 4 + wave;
    if (n >= NN) return;
    int start = offs[n];
    int end = (n + 1 < NN) ? offs[n + 1] : ETOT;
    int deg = end - start;
    // ---- pass 1: denominators (group g = lane>>5) ----
    int g = lane >> 5, sub = lane & 31;
    float edg = ed[n * 2 + g];
    float dsum = 0.f;
    for (int j = sub; j < deg; j += 32) {
        int s = csrc[start + j];
        dsum += __expf(leaky(es[s * 2 + g] + edg));
    }
    for (int off = 1; off < 32; off <<= 1) dsum += __shfl_xor(dsum, off);
    float inv = 1.f / (dsum + 1e-16f);
    // ---- pass 2: 8 edges/iter; 8 lanes per edge cover 64 ch ----
    int slot = lane >> 3;       // edge slot 0..7
    int le = lane & 7;
    int g2 = le >> 2;           // channel-half: 0=mean, 1=log_std
    int c8 = le * 8;
    float invg = __shfl(inv, g2 << 5);
    float edg2 = __shfl(edg, g2 << 5);
    float accv[8] = {};
    for (int j = slot; j < deg; j += 8) {
        int p = start + j;
        int s = csrc[p];
        float a = __expf(leaky(es[s * 2 + g2] + edg2)) * invg;
        if (le == 0) a_wm[ceid[p]] = a;
        else if (le == 4) a_ws[ceid[p]] = a;
        f16x8 v = *(const f16x8*)(H + (size_t)s * 64 + c8);
#pragma unroll
        for (int k = 0; k < 8; ++k) accv[k] += a * (float)v[k];
    }
    // reduce over edge slots (lane bits 3,4,5)
#pragma unroll
    for (int k = 0; k < 8; ++k) {
        accv[k] += __shfl_xor(accv[k], 8);
        accv[k] += __shfl_xor(accv[k], 16);
        accv[k] += __shfl_xor(accv[k], 32);
    }
    if (lane < 4) {
        float4 r0, r1;
        int cb = lane * 8;
        r0.x = accv[0] + bm[cb + 0]; r0.y = accv[1] + bm[cb + 1];
        r0.z = accv[2] + bm[cb + 2]; r0.w = accv[3] + bm[cb + 3];
        r1.x = accv[4] + bm[cb + 4]; r1.y = accv[5] + bm[cb + 5];
        r1.z = accv[6] + bm[cb + 6]; r1.w = accv[7] + bm[cb + 7];
        *(float4*)(zmean + (size_t)n * 32 + cb) = r0;
        *(float4*)(zmean + (size_t)n * 32 + cb + 4) = r1;
    } else if (lane < 8) {
        float4 r0, r1;
        int cb = (lane - 4) * 8;
        r0.x = accv[0] + bs[cb + 0]; r0.y = accv[1] + bs[cb + 1];
        r0.z = accv[2] + bs[cb + 2]; r0.w = accv[3] + bs[cb + 3];
        r1.x = accv[4] + bs[cb + 4]; r1.y = accv[5] + bs[cb + 5];
        r1.z = accv[6] + bs[cb + 6]; r1.w = accv[7] + bs[cb + 7];
        *(float4*)(zlog + (size_t)n * 32 + cb) = r0;
        *(float4*)(zlog + (size_t)n * 32 + cb + 4) = r1;
    }
}

// ---------------- launch ----------------

extern "C" void kernel_launch(void* const* d_in, const int* in_sizes, int n_in,
                              void* d_out, int out_size, void* d_ws, size_t ws_size,
                              hipStream_t stream) {
    const float* x   = (const float*)d_in[0];
    const int*   ei  = (const int*)d_in[1];
    const float* W1  = (const float*)d_in[2];
    const float* a1s = (const float*)d_in[3];
    const float* a1d = (const float*)d_in[4];
    const float* b1  = (const float*)d_in[5];
    const float* W2  = (const float*)d_in[6];
    const float* a2s = (const float*)d_in[7];
    const float* a2d = (const float*)d_in[8];
    const float* b2  = (const float*)d_in[9];
    const float* Wm  = (const float*)d_in[10];
    const float* ams = (const float*)d_in[11];
    const float* amd = (const float*)d_in[12];
    const float* bm  = (const float*)d_in[13];
    const float* Ws  = (const float*)d_in[14];
    const float* ass = (const float*)d_in[15];
    const float* asd = (const float*)d_in[16];
    const float* bs  = (const float*)d_in[17];

    float* out = (float*)d_out;
    float* zmean = out;                       // [50000,32]
    float* zlog  = out + 1600000;             // [50000,32]
    float* a_w1  = out + 3200000;             // [850000,4]
    float* a_w2  = out + 6600000;             // [850000,4]
    float* a_wm  = out + 10000000;            // [850000]
    float* a_ws_o = out + 10850000;           // [850000]

    float* ws = (float*)d_ws;
    size_t o = 0;
    f16*   Hh   = (f16*)(ws + o); o += (size_t)NN * 128;  // GEMM out [NN,256] f16, reused each layer
    f16*   h1h  = (f16*)(ws + o); o += (size_t)NN * 128;  // relu(h1) f16 (GEMM2 A)
    f16*   h2h  = (f16*)(ws + o); o += (size_t)NN * 32;   // h2 f16 [NN,64] (GEMM3 A)
    float* es1  = ws + o; o += NN * 4;
    float* ed1  = ws + o; o += NN * 4;
    float* es2  = ws + o; o += NN * 4;
    float* ed2  = ws + o; o += NN * 4;
    float* esms = ws + o; o += NN * 2;
    float* edms = ws + o; o += NN * 2;
    f16*   Wt1  = (f16*)(ws + o); o += 32768;      // [256][256] f16 transposed
    f16*   Wt2  = (f16*)(ws + o); o += 32768;
    f16*   Wtms = (f16*)(ws + o); o += 2048;       // [64][64] f16 transposed
    float* aSms = ws + o; o += 64;
    float* aDms = ws + o; o += 64;
    int* deg    = (int*)(ws + o); o += NN;
    int* offs   = (int*)(ws + o); o += NN;
    int* cursor = (int*)(ws + o); o += NN;
    int* csrc   = (int*)(ws + o); o += ETOT;
    int* ceid   = (int*)(ws + o); o += ETOT;

    const int edgeBlocks = (ETOT + 255) / 256;   // 3321
    const int nodeBlocks = (NN + 255) / 256;     // 196
    const int waveBlocks = (NN + 3) / 4;         // 12500

    // ---- CSR build ----
    hipMemsetAsync(deg, 0, NN * sizeof(int), stream);
    deg_kernel<<<edgeBlocks, 256, 0, stream>>>(ei, deg);
    scan1_kernel<<<nodeBlocks, 256, 0, stream>>>(deg, offs, cursor /*tmp bsum*/, NN);
    scan2_kernel<<<1, 256, 0, stream>>>(cursor, nodeBlocks);
    scan3_kernel<<<nodeBlocks, 256, 0, stream>>>(cursor, offs, deg /*reuse as cursor*/, NN);
    fill_kernel<<<edgeBlocks, 256, 0, stream>>>(ei, deg, csrc, ceid);

    // ---- pack weights (f16 + transpose) ----
    packw_kernel<<<256, 256, 0, stream>>>(W1, W2, Wm, Ws, ams, ass, amd, asd, Wt1, Wt2, Wtms, aSms, aDms);

    dim3 gg1(4, (NN + 127) / 128);   // N=256 / BN=64, M tiles of 128
    dim3 gg3(1, (NN + 127) / 128);   // N=64
    // ---- layer 1 ----
    mfma_gemm<256, true><<<gg1, 256, 0, stream>>>(x, Wt1, Hh, NN, 256);
    scores4_kernel<<<waveBlocks, 256, 0, stream>>>(Hh, a1s, a1d, es1, ed1);
    agg_concat_kernel<<<waveBlocks, 256, 0, stream>>>(Hh, es1, ed1, offs, csrc, ceid, b1, h1h, a_w1);

    // ---- layer 2 ----
    mfma_gemm<256, false><<<gg1, 256, 0, stream>>>(h1h, Wt2, Hh, NN, 256);
    scores4_kernel<<<waveBlocks, 256, 0, stream>>>(Hh, a2s, a2d, es2, ed2);
    agg_mean_kernel<<<waveBlocks, 256, 0, stream>>>(Hh, es2, ed2, offs, csrc, ceid, b2, h2h, a_w2);

    // ---- mean / log_std heads ----
    mfma_gemm<64, false><<<gg3, 256, 0, stream>>>(h2h, Wtms, Hh, NN, 64);
    scores_ms_kernel<<<waveBlocks, 256, 0, stream>>>(Hh, aSms, aDms, esms, edms);
    agg_ms_kernel<<<waveBlocks, 256, 0, stream>>>(Hh, esms, edms, offs, csrc, ceid, bm, bs,
                                                  zmean, zlog, a_wm, a_ws_o);
}

// Round 4
// 544.020 us; speedup vs baseline: 1.4711x; 1.0048x over previous
//
#include <hip/hip_runtime.h>
#include <cstdint>
#include <cstddef>

#define NN 50000
#define EE 800000
#define ETOT 850000   // EE + NN self loops
#define NEG_SLOPE 0.2f

typedef _Float16 f16;
typedef __attribute__((ext_vector_type(4))) _Float16 f16x4;
typedef __attribute__((ext_vector_type(8))) _Float16 f16x8;
typedef __attribute__((ext_vector_type(4))) float f32x4;

// ---------------- CSR build ----------------

__global__ __launch_bounds__(256) void deg_kernel(const int* __restrict__ ei, int* __restrict__ deg) {
    int e = blockIdx.x * 256 + threadIdx.x;
    if (e >= ETOT) return;
    int d = (e < EE) ? ei[EE + e] : (e - EE);
    atomicAdd(&deg[d], 1);
}

__global__ __launch_bounds__(256) void scan1_kernel(const int* __restrict__ deg, int* __restrict__ offs,
                                                    int* __restrict__ bsum, int n) {
    __shared__ int sh[256];
    int i = blockIdx.x * 256 + threadIdx.x;
    int v = (i < n) ? deg[i] : 0;
    sh[threadIdx.x] = v;
    __syncthreads();
    for (int off = 1; off < 256; off <<= 1) {
        int t = (threadIdx.x >= off) ? sh[threadIdx.x - off] : 0;
        __syncthreads();
        sh[threadIdx.x] += t;
        __syncthreads();
    }
    if (i < n) offs[i] = sh[threadIdx.x] - v;   // exclusive within block
    if (threadIdx.x == 255) bsum[blockIdx.x] = sh[255];
}

__global__ __launch_bounds__(256) void scan2_kernel(int* __restrict__ bsum, int nb) {
    __shared__ int sh[256];
    int v = (threadIdx.x < nb) ? bsum[threadIdx.x] : 0;
    sh[threadIdx.x] = v;
    __syncthreads();
    for (int off = 1; off < 256; off <<= 1) {
        int t = (threadIdx.x >= off) ? sh[threadIdx.x - off] : 0;
        __syncthreads();
        sh[threadIdx.x] += t;
        __syncthreads();
    }
    if (threadIdx.x < nb) bsum[threadIdx.x] = sh[threadIdx.x] - v;  // exclusive
}

__global__ __launch_bounds__(256) void scan3_kernel(const int* __restrict__ bsum, int* __restrict__ offs,
                                                    int* __restrict__ cursor, int n) {
    int i = blockIdx.x * 256 + threadIdx.x;
    if (i < n) {
        int o = offs[i] + bsum[blockIdx.x];
        offs[i] = o;
        cursor[i] = o;
    }
}

__global__ __launch_bounds__(256) void fill_kernel(const int* __restrict__ ei, int* __restrict__ cursor,
                                                   int* __restrict__ csrc) {
    int e = blockIdx.x * 256 + threadIdx.x;
    if (e >= ETOT) return;
    int d, s;
    if (e < EE) { s = ei[e]; d = ei[EE + e]; } else { s = e - EE; d = e - EE; }
    int p = atomicAdd(&cursor[d], 1);
    csrc[p] = s;
}

// ---------------- MFMA GEMM: A[MxK] (f32 or f16) * Wt[N][K]^T -> C f16 [MxN] ----------------

template<int K, bool AF32>
__global__ __launch_bounds__(256) void mfma_gemm(const void* __restrict__ Ap, const f16* __restrict__ Bt,
                                                 f16* __restrict__ C, int M, int N) {
    int w = threadIdx.x >> 6, lane = threadIdx.x & 63;
    int m0 = blockIdx.y * 128 + w * 32;
    int n0 = blockIdx.x * 64;
    int r = lane & 15, kb = lane >> 4;
    int ar0 = m0 + r;       if (ar0 > M - 1) ar0 = M - 1;
    int ar1 = m0 + 16 + r;  if (ar1 > M - 1) ar1 = M - 1;
    f32x4 acc[2][4] = {};
    const float* Af = (const float*)Ap;
    const f16*   Ah = (const f16*)Ap;
    size_t a0off = (size_t)ar0 * K + kb * 8;
    size_t a1off = (size_t)ar1 * K + kb * 8;
    const f16* bbase = Bt + (size_t)(n0 + r) * K + kb * 8;
    for (int k0 = 0; k0 < K; k0 += 32) {
        f16x8 a0, a1;
        if constexpr (AF32) {
            float4 l0 = *(const float4*)(Af + a0off + k0);
            float4 h0 = *(const float4*)(Af + a0off + k0 + 4);
            float4 l1 = *(const float4*)(Af + a1off + k0);
            float4 h1 = *(const float4*)(Af + a1off + k0 + 4);
            a0[0]=(f16)l0.x; a0[1]=(f16)l0.y; a0[2]=(f16)l0.z; a0[3]=(f16)l0.w;
            a0[4]=(f16)h0.x; a0[5]=(f16)h0.y; a0[6]=(f16)h0.z; a0[7]=(f16)h0.w;
            a1[0]=(f16)l1.x; a1[1]=(f16)l1.y; a1[2]=(f16)l1.z; a1[3]=(f16)l1.w;
            a1[4]=(f16)h1.x; a1[5]=(f16)h1.y; a1[6]=(f16)h1.z; a1[7]=(f16)h1.w;
        } else {
            a0 = *(const f16x8*)(Ah + a0off + k0);
            a1 = *(const f16x8*)(Ah + a1off + k0);
        }
#pragma unroll
        for (int ni = 0; ni < 4; ++ni) {
            f16x8 b = *(const f16x8*)(bbase + (size_t)ni * 16 * K + k0);
            acc[0][ni] = __builtin_amdgcn_mfma_f32_16x16x32_f16(a0, b, acc[0][ni], 0, 0, 0);
            acc[1][ni] = __builtin_amdgcn_mfma_f32_16x16x32_f16(a1, b, acc[1][ni], 0, 0, 0);
        }
    }
#pragma unroll
    for (int mi = 0; mi < 2; ++mi) {
#pragma unroll
        for (int i = 0; i < 4; ++i) {
            int row = m0 + mi * 16 + kb * 4 + i;
            if (row < M) {
#pragma unroll
                for (int ni = 0; ni < 4; ++ni)
                    C[(size_t)row * N + n0 + ni * 16 + r] = (f16)acc[mi][ni][i];
            }
        }
    }
}

// ---------------- pack weights: f16 + transpose (Wt[N][K]) ----------------

__global__ __launch_bounds__(256) void packw_kernel(const float* __restrict__ W1, const float* __restrict__ W2,
                                                    const float* __restrict__ Wm, const float* __restrict__ Ws,
                                                    const float* __restrict__ ams, const float* __restrict__ ass,
                                                    const float* __restrict__ amd, const float* __restrict__ asd,
                                                    f16* __restrict__ Wt1, f16* __restrict__ Wt2,
                                                    f16* __restrict__ Wtms,
                                                    float* __restrict__ aS, float* __restrict__ aD) {
    int i = blockIdx.x * 256 + threadIdx.x;
    if (i < 65536) {
        int n = i >> 8, k = i & 255;   // Wt[n][k] = W[k][n]
        Wt1[(size_t)n * 256 + k] = (f16)W1[(size_t)k * 256 + n];
        Wt2[(size_t)n * 256 + k] = (f16)W2[(size_t)k * 256 + n];
    }
    if (i < 4096) {
        int c = i >> 6, k = i & 63;    // Wtms[c][k]: c<32 -> Wm[k][c], else Ws[k][c-32]
        float v = (c < 32) ? Wm[k * 32 + c] : Ws[k * 32 + (c - 32)];
        Wtms[(size_t)c * 64 + k] = (f16)v;
    }
    if (i < 64) {
        aS[i] = (i < 32) ? ams[i] : ass[i - 32];
        aD[i] = (i < 32) ? amd[i] : asd[i - 32];
    }
}

// ---------------- attention score dots (fp16 H) ----------------

__global__ __launch_bounds__(256) void scores4_kernel(const f16* __restrict__ H, const float* __restrict__ aS,
                                                      const float* __restrict__ aD, float* __restrict__ es,
                                                      float* __restrict__ ed) {
    int wave = threadIdx.x >> 6, lane = threadIdx.x & 63;
    int n = blockIdx.x * 4 + wave;
    if (n >= NN) return;
    f16x4 h = *(const f16x4*)(H + (size_t)n * 256 + lane * 4);
    float4 s4 = *(const float4*)(aS + lane * 4);
    float4 d4 = *(const float4*)(aD + lane * 4);
    float hx = (float)h[0], hy = (float)h[1], hz = (float)h[2], hw = (float)h[3];
    float ps = hx * s4.x + hy * s4.y + hz * s4.z + hw * s4.w;
    float pd = hx * d4.x + hy * d4.y + hz * d4.z + hw * d4.w;
    for (int off = 1; off < 16; off <<= 1) { ps += __shfl_xor(ps, off); pd += __shfl_xor(pd, off); }
    if ((lane & 15) == 0) {
        int hh = lane >> 4;
        es[n * 4 + hh] = ps;
        ed[n * 4 + hh] = pd;
    }
}

__global__ __launch_bounds__(256) void scores_ms_kernel(const f16* __restrict__ H, const float* __restrict__ aS,
                                                        const float* __restrict__ aD, float* __restrict__ es,
                                                        float* __restrict__ ed) {
    int wave = threadIdx.x >> 6, lane = threadIdx.x & 63;
    int n = blockIdx.x * 4 + wave;
    if (n >= NN) return;
    float h = (float)H[(size_t)n * 64 + lane];
    float ps = h * aS[lane];
    float pd = h * aD[lane];
    for (int off = 1; off < 32; off <<= 1) { ps += __shfl_xor(ps, off); pd += __shfl_xor(pd, off); }
    if ((lane & 31) == 0) {
        int g = lane >> 5;
        es[n * 2 + g] = ps;
        ed[n * 2 + g] = pd;
    }
}

__device__ __forceinline__ float leaky(float v) { return v > 0.f ? v : NEG_SLOPE * v; }

// ---------------- edge-parallel alpha writers (coalesced) ----------------

__global__ __launch_bounds__(256) void alpha4_kernel(const int* __restrict__ ei, const float* __restrict__ es,
                                                     const float* __restrict__ ed, const float* __restrict__ inv,
                                                     float* __restrict__ out4) {
    int e = blockIdx.x * 256 + threadIdx.x;
    if (e >= ETOT) return;
    int s, d;
    if (e < EE) { s = ei[e]; d = ei[EE + e]; } else { s = e - EE; d = e - EE; }
    float4 esv = *(const float4*)(es + (size_t)s * 4);
    float4 edv = *(const float4*)(ed + (size_t)d * 4);
    float4 iv  = *(const float4*)(inv + (size_t)d * 4);
    float4 r;
    r.x = __expf(leaky(esv.x + edv.x)) * iv.x;
    r.y = __expf(leaky(esv.y + edv.y)) * iv.y;
    r.z = __expf(leaky(esv.z + edv.z)) * iv.z;
    r.w = __expf(leaky(esv.w + edv.w)) * iv.w;
    *(float4*)(out4 + (size_t)e * 4) = r;
}

__global__ __launch_bounds__(256) void alpha_ms_kernel(const int* __restrict__ ei, const float* __restrict__ es,
                                                       const float* __restrict__ ed, const float* __restrict__ inv,
                                                       float* __restrict__ awm, float* __restrict__ aws) {
    int e = blockIdx.x * 256 + threadIdx.x;
    if (e >= ETOT) return;
    int s, d;
    if (e < EE) { s = ei[e]; d = ei[EE + e]; } else { s = e - EE; d = e - EE; }
    float2 esv = *(const float2*)(es + (size_t)s * 2);
    float2 edv = *(const float2*)(ed + (size_t)d * 2);
    float2 iv  = *(const float2*)(inv + (size_t)d * 2);
    awm[e] = __expf(leaky(esv.x + edv.x)) * iv.x;
    aws[e] = __expf(leaky(esv.y + edv.y)) * iv.y;
}

// ---------------- layer-1 aggregation: online softmax, 16B gathers, no alpha scatter ----------------
// 128-thread blocks (2 nodes/block) to cut degree-imbalance convoying.

__global__ __launch_bounds__(128) void agg_concat_kernel(
    const f16* __restrict__ H, const float* __restrict__ es, const float* __restrict__ ed,
    const int* __restrict__ offs, const int* __restrict__ csrc,
    const float* __restrict__ bias, f16* __restrict__ out, float* __restrict__ invout) {
    int wave = threadIdx.x >> 6, lane = threadIdx.x & 63;
    int n = blockIdx.x * 2 + wave;
    if (n >= NN) return;
    int start = offs[n];
    int end = (n + 1 < NN) ? offs[n + 1] : ETOT;
    int deg = end - start;
    // ---- pass 1: denominators ----
    int h16 = lane >> 4, sub = lane & 15;
    float edh = ed[n * 4 + h16];
    float dsum = 0.f;
    for (int j = sub; j < deg; j += 16) {
        int s = csrc[start + j];
        dsum += __expf(leaky(es[s * 4 + h16] + edh));
    }
    for (int off = 1; off < 16; off <<= 1) dsum += __shfl_xor(dsum, off);
    float inv = 1.f / (dsum + 1e-16f);
    if (sub == 0) invout[n * 4 + h16] = inv;
    // ---- pass 2: aggregate ----
    int half = lane >> 5;          // edge slot (2 edges per iteration)
    int l5 = lane & 31;
    int hh = l5 >> 3;              // head owning channels c8..c8+7
    int c8 = l5 * 8;
    float invh = __shfl(inv, hh << 4);
    float edhh = __shfl(edh, hh << 4);
    float accv[8] = {};
    int j = half;
    for (; j + 6 < deg; j += 8) {
        int p0 = start + j, p1 = start + j + 2, p2 = start + j + 4, p3 = start + j + 6;
        int s0 = csrc[p0], s1 = csrc[p1], s2 = csrc[p2], s3 = csrc[p3];
        float a0 = __expf(leaky(es[s0 * 4 + hh] + edhh)) * invh;
        float a1 = __expf(leaky(es[s1 * 4 + hh] + edhh)) * invh;
        float a2 = __expf(leaky(es[s2 * 4 + hh] + edhh)) * invh;
        float a3 = __expf(leaky(es[s3 * 4 + hh] + edhh)) * invh;
        f16x8 v0 = *(const f16x8*)(H + (size_t)s0 * 256 + c8);
        f16x8 v1 = *(const f16x8*)(H + (size_t)s1 * 256 + c8);
        f16x8 v2 = *(const f16x8*)(H + (size_t)s2 * 256 + c8);
        f16x8 v3 = *(const f16x8*)(H + (size_t)s3 * 256 + c8);
#pragma unroll
        for (int k = 0; k < 8; ++k)
            accv[k] += a0 * (float)v0[k] + a1 * (float)v1[k] + a2 * (float)v2[k] + a3 * (float)v3[k];
    }
    for (; j < deg; j += 2) {
        int p0 = start + j;
        int s0 = csrc[p0];
        float a0 = __expf(leaky(es[s0 * 4 + hh] + edhh)) * invh;
        f16x8 v0 = *(const f16x8*)(H + (size_t)s0 * 256 + c8);
#pragma unroll
        for (int k = 0; k < 8; ++k) accv[k] += a0 * (float)v0[k];
    }
#pragma unroll
    for (int k = 0; k < 8; ++k) accv[k] += __shfl_xor(accv[k], 32);
    if (lane < 32) {
        f16x8 r;
#pragma unroll
        for (int k = 0; k < 8; ++k) r[k] = (f16)fmaxf(accv[k] + bias[c8 + k], 0.f);
        *(f16x8*)(out + (size_t)n * 256 + c8) = r;
    }
}

// ---------------- layer-2 aggregation (mean over 4 heads), same structure ----------------

__global__ __launch_bounds__(128) void agg_mean_kernel(
    const f16* __restrict__ H, const float* __restrict__ es, const float* __restrict__ ed,
    const int* __restrict__ offs, const int* __restrict__ csrc,
    const float* __restrict__ bias, f16* __restrict__ out, float* __restrict__ invout) {
    int wave = threadIdx.x >> 6, lane = threadIdx.x & 63;
    int n = blockIdx.x * 2 + wave;
    if (n >= NN) return;
    int start = offs[n];
    int end = (n + 1 < NN) ? offs[n + 1] : ETOT;
    int deg = end - start;
    int h16 = lane >> 4, sub = lane & 15;
    float edh = ed[n * 4 + h16];
    float dsum = 0.f;
    for (int j = sub; j < deg; j += 16) {
        int s = csrc[start + j];
        dsum += __expf(leaky(es[s * 4 + h16] + edh));
    }
    for (int off = 1; off < 16; off <<= 1) dsum += __shfl_xor(dsum, off);
    float inv = 1.f / (dsum + 1e-16f);
    if (sub == 0) invout[n * 4 + h16] = inv;
    int half = lane >> 5;
    int l5 = lane & 31;
    int hh = l5 >> 3;
    int c8 = l5 * 8;
    float invh = __shfl(inv, hh << 4);
    float edhh = __shfl(edh, hh << 4);
    float accv[8] = {};
    int j = half;
    for (; j + 6 < deg; j += 8) {
        int p0 = start + j, p1 = start + j + 2, p2 = start + j + 4, p3 = start + j + 6;
        int s0 = csrc[p0], s1 = csrc[p1], s2 = csrc[p2], s3 = csrc[p3];
        float a0 = __expf(leaky(es[s0 * 4 + hh] + edhh)) * invh;
        float a1 = __expf(leaky(es[s1 * 4 + hh] + edhh)) * invh;
        float a2 = __expf(leaky(es[s2 * 4 + hh] + edhh)) * invh;
        float a3 = __expf(leaky(es[s3 * 4 + hh] + edhh)) * invh;
        f16x8 v0 = *(const f16x8*)(H + (size_t)s0 * 256 + c8);
        f16x8 v1 = *(const f16x8*)(H + (size_t)s1 * 256 + c8);
        f16x8 v2 = *(const f16x8*)(H + (size_t)s2 * 256 + c8);
        f16x8 v3 = *(const f16x8*)(H + (size_t)s3 * 256 + c8);
#pragma unroll
        for (int k = 0; k < 8; ++k)
            accv[k] += a0 * (float)v0[k] + a1 * (float)v1[k] + a2 * (float)v2[k] + a3 * (float)v3[k];
    }
    for (; j < deg; j += 2) {
        int p0 = start + j;
        int s0 = csrc[p0];
        float a0 = __expf(leaky(es[s0 * 4 + hh] + edhh)) * invh;
        f16x8 v0 = *(const f16x8*)(H + (size_t)s0 * 256 + c8);
#pragma unroll
        for (int k = 0; k < 8; ++k) accv[k] += a0 * (float)v0[k];
    }
    // reduce over heads (lane bits 3,4) and edge-half (bit 5)
#pragma unroll
    for (int k = 0; k < 8; ++k) {
        accv[k] += __shfl_xor(accv[k], 8);
        accv[k] += __shfl_xor(accv[k], 16);
        accv[k] += __shfl_xor(accv[k], 32);
    }
    if (lane < 8) {
        f16x8 r;
#pragma unroll
        for (int k = 0; k < 8; ++k) r[k] = (f16)fmaxf(accv[k] * 0.25f + bias[lane * 8 + k], 0.f);
        *(f16x8*)(out + (size_t)n * 64 + lane * 8) = r;
    }
}

// ---------------- mean/log_std heads aggregation: 8 edges/iter, 16B gathers ----------------

__global__ __launch_bounds__(128) void agg_ms_kernel(
    const f16* __restrict__ H, const float* __restrict__ es, const float* __restrict__ ed,
    const int* __restrict__ offs, const int* __restrict__ csrc,
    const float* __restrict__ bm, const float* __restrict__ bs,
    float* __restrict__ zmean, float* __restrict__ zlog, float* __restrict__ invout) {
    int wave = threadIdx.x >> 6, lane = threadIdx.x & 63;
    int n = blockIdx.x * 2 + wave;
    if (n >= NN) return;
    int start = offs[n];
    int end = (n + 1 < NN) ? offs[n + 1] : ETOT;
    int deg = end - start;
    // ---- pass 1: denominators (group g = lane>>5) ----
    int g = lane >> 5, sub = lane & 31;
    float edg = ed[n * 2 + g];
    float dsum = 0.f;
    for (int j = sub; j < deg; j += 32) {
        int s = csrc[start + j];
        dsum += __expf(leaky(es[s * 2 + g] + edg));
    }
    for (int off = 1; off < 32; off <<= 1) dsum += __shfl_xor(dsum, off);
    float inv = 1.f / (dsum + 1e-16f);
    if (sub == 0) invout[n * 2 + g] = inv;
    // ---- pass 2: 8 edges/iter; 8 lanes per edge cover 64 ch ----
    int slot = lane >> 3;       // edge slot 0..7
    int le = lane & 7;
    int g2 = le >> 2;           // channel-half: 0=mean, 1=log_std
    int c8 = le * 8;
    float invg = __shfl(inv, g2 << 5);
    float edg2 = __shfl(edg, g2 << 5);
    float accv[8] = {};
    for (int j = slot; j < deg; j += 8) {
        int p = start + j;
        int s = csrc[p];
        float a = __expf(leaky(es[s * 2 + g2] + edg2)) * invg;
        f16x8 v = *(const f16x8*)(H + (size_t)s * 64 + c8);
#pragma unroll
        for (int k = 0; k < 8; ++k) accv[k] += a * (float)v[k];
    }
    // reduce over edge slots (lane bits 3,4,5)
#pragma unroll
    for (int k = 0; k < 8; ++k) {
        accv[k] += __shfl_xor(accv[k], 8);
        accv[k] += __shfl_xor(accv[k], 16);
        accv[k] += __shfl_xor(accv[k], 32);
    }
    if (lane < 4) {
        float4 r0, r1;
        int cb = lane * 8;
        r0.x = accv[0] + bm[cb + 0]; r0.y = accv[1] + bm[cb + 1];
        r0.z = accv[2] + bm[cb + 2]; r0.w = accv[3] + bm[cb + 3];
        r1.x = accv[4] + bm[cb + 4]; r1.y = accv[5] + bm[cb + 5];
        r1.z = accv[6] + bm[cb + 6]; r1.w = accv[7] + bm[cb + 7];
        *(float4*)(zmean + (size_t)n * 32 + cb) = r0;
        *(float4*)(zmean + (size_t)n * 32 + cb + 4) = r1;
    } else if (lane < 8) {
        float4 r0, r1;
        int cb = (lane - 4) * 8;
        r0.x = accv[0] + bs[cb + 0]; r0.y = accv[1] + bs[cb + 1];
        r0.z = accv[2] + bs[cb + 2]; r0.w = accv[3] + bs[cb + 3];
        r1.x = accv[4] + bs[cb + 4]; r1.y = accv[5] + bs[cb + 5];
        r1.z = accv[6] + bs[cb + 6]; r1.w = accv[7] + bs[cb + 7];
        *(float4*)(zlog + (size_t)n * 32 + cb) = r0;
        *(float4*)(zlog + (size_t)n * 32 + cb + 4) = r1;
    }
}

// ---------------- launch ----------------

extern "C" void kernel_launch(void* const* d_in, const int* in_sizes, int n_in,
                              void* d_out, int out_size, void* d_ws, size_t ws_size,
                              hipStream_t stream) {
    const float* x   = (const float*)d_in[0];
    const int*   ei  = (const int*)d_in[1];
    const float* W1  = (const float*)d_in[2];
    const float* a1s = (const float*)d_in[3];
    const float* a1d = (const float*)d_in[4];
    const float* b1  = (const float*)d_in[5];
    const float* W2  = (const float*)d_in[6];
    const float* a2s = (const float*)d_in[7];
    const float* a2d = (const float*)d_in[8];
    const float* b2  = (const float*)d_in[9];
    const float* Wm  = (const float*)d_in[10];
    const float* ams = (const float*)d_in[11];
    const float* amd = (const float*)d_in[12];
    const float* bm  = (const float*)d_in[13];
    const float* Ws  = (const float*)d_in[14];
    const float* ass = (const float*)d_in[15];
    const float* asd = (const float*)d_in[16];
    const float* bs  = (const float*)d_in[17];

    float* out = (float*)d_out;
    float* zmean = out;                       // [50000,32]
    float* zlog  = out + 1600000;             // [50000,32]
    float* a_w1  = out + 3200000;             // [850000,4]
    float* a_w2  = out + 6600000;             // [850000,4]
    float* a_wm  = out + 10000000;            // [850000]
    float* a_ws_o = out + 10850000;           // [850000]

    float* ws = (float*)d_ws;
    size_t o = 0;
    f16*   Hh   = (f16*)(ws + o); o += (size_t)NN * 128;  // GEMM out [NN,256] f16, reused each layer
    f16*   h1h  = (f16*)(ws + o); o += (size_t)NN * 128;  // relu(h1) f16 (GEMM2 A)
    f16*   h2h  = (f16*)(ws + o); o += (size_t)NN * 32;   // h2 f16 [NN,64] (GEMM3 A)
    float* es1  = ws + o; o += NN * 4;
    float* ed1  = ws + o; o += NN * 4;
    float* es2  = ws + o; o += NN * 4;
    float* ed2  = ws + o; o += NN * 4;
    float* esms = ws + o; o += NN * 2;
    float* edms = ws + o; o += NN * 2;
    float* inv1 = ws + o; o += NN * 4;
    float* inv2 = ws + o; o += NN * 4;
    float* invms= ws + o; o += NN * 2;
    f16*   Wt1  = (f16*)(ws + o); o += 32768;      // [256][256] f16 transposed
    f16*   Wt2  = (f16*)(ws + o); o += 32768;
    f16*   Wtms = (f16*)(ws + o); o += 2048;       // [64][64] f16 transposed
    float* aSms = ws + o; o += 64;
    float* aDms = ws + o; o += 64;
    int* deg    = (int*)(ws + o); o += NN;
    int* offs   = (int*)(ws + o); o += NN;
    int* cursor = (int*)(ws + o); o += NN;
    int* csrc   = (int*)(ws + o); o += ETOT;

    const int edgeBlocks = (ETOT + 255) / 256;   // 3321
    const int nodeBlocks = (NN + 255) / 256;     // 196
    const int waveBlocks = (NN + 3) / 4;         // 12500 (4 nodes/block kernels)
    const int aggBlocks  = (NN + 1) / 2;         // 25000 (2 nodes/block kernels)

    // ---- CSR build ----
    hipMemsetAsync(deg, 0, NN * sizeof(int), stream);
    deg_kernel<<<edgeBlocks, 256, 0, stream>>>(ei, deg);
    scan1_kernel<<<nodeBlocks, 256, 0, stream>>>(deg, offs, cursor /*tmp bsum*/, NN);
    scan2_kernel<<<1, 256, 0, stream>>>(cursor, nodeBlocks);
    scan3_kernel<<<nodeBlocks, 256, 0, stream>>>(cursor, offs, deg /*reuse as cursor*/, NN);
    fill_kernel<<<edgeBlocks, 256, 0, stream>>>(ei, deg, csrc);

    // ---- pack weights (f16 + transpose) ----
    packw_kernel<<<256, 256, 0, stream>>>(W1, W2, Wm, Ws, ams, ass, amd, asd, Wt1, Wt2, Wtms, aSms, aDms);

    dim3 gg1(4, (NN + 127) / 128);   // N=256 / BN=64, M tiles of 128
    dim3 gg3(1, (NN + 127) / 128);   // N=64
    // ---- layer 1 ----
    mfma_gemm<256, true><<<gg1, 256, 0, stream>>>(x, Wt1, Hh, NN, 256);
    scores4_kernel<<<waveBlocks, 256, 0, stream>>>(Hh, a1s, a1d, es1, ed1);
    agg_concat_kernel<<<aggBlocks, 128, 0, stream>>>(Hh, es1, ed1, offs, csrc, b1, h1h, inv1);
    alpha4_kernel<<<edgeBlocks, 256, 0, stream>>>(ei, es1, ed1, inv1, a_w1);

    // ---- layer 2 ----
    mfma_gemm<256, false><<<gg1, 256, 0, stream>>>(h1h, Wt2, Hh, NN, 256);
    scores4_kernel<<<waveBlocks, 256, 0, stream>>>(Hh, a2s, a2d, es2, ed2);
    agg_mean_kernel<<<aggBlocks, 128, 0, stream>>>(Hh, es2, ed2, offs, csrc, b2, h2h, inv2);
    alpha4_kernel<<<edgeBlocks, 256, 0, stream>>>(ei, es2, ed2, inv2, a_w2);

    // ---- mean / log_std heads ----
    mfma_gemm<64, false><<<gg3, 256, 0, stream>>>(h2h, Wtms, Hh, NN, 64);
    scores_ms_kernel<<<waveBlocks, 256, 0, stream>>>(Hh, aSms, aDms, esms, edms);
    agg_ms_kernel<<<aggBlocks, 128, 0, stream>>>(Hh, esms, edms, offs, csrc, bm, bs,
                                                 zmean, zlog, invms);
    alpha_ms_kernel<<<edgeBlocks, 256, 0, stream>>>(ei, esms, edms, invms, a_wm, a_ws_o);
}